// Round 1
// baseline (551.454 us; speedup 1.0000x reference)
//
#include <hip/hip_runtime.h>

using short8 = __attribute__((ext_vector_type(8))) short;
using f32x4  = __attribute__((ext_vector_type(4))) float;
using u32x2  = __attribute__((ext_vector_type(2))) unsigned int;
using u32x4  = __attribute__((ext_vector_type(4))) unsigned int;

#define MFMA16(a, b, c) __builtin_amdgcn_mfma_f32_16x16x32_bf16((a), (b), (c), 0, 0, 0)

__device__ inline float bf2f(ushort v) { return __uint_as_float(((unsigned int)v) << 16); }
__device__ inline unsigned int f2bfu(float f) {
  unsigned int u = __float_as_uint(f);
  return (u + 0x7fffu + ((u >> 16) & 1u)) >> 16;   // RNE
}
__device__ inline unsigned int pk2(float a, float b) { return f2bfu(a) | (f2bfu(b) << 16); }

__device__ inline void gl_lds16(const ushort* g, ushort* l) {
  __builtin_amdgcn_global_load_lds(
      (const __attribute__((address_space(1))) void*)g,
      (__attribute__((address_space(3))) void*)l, 16, 0, 0);
}

// ---------------- fp32 -> bf16 convert, 8 elems/thread ----------------
__global__ __launch_bounds__(256) void f2b8(const float* __restrict__ src,
                                            ushort* __restrict__ dst, int n) {
  int i = (blockIdx.x * 256 + threadIdx.x) * 8;
  if (i >= n) return;
  f32x4 a = *(const f32x4*)(src + i);
  f32x4 b = *(const f32x4*)(src + i + 4);
  u32x4 o;
  o[0] = pk2(a[0], a[1]); o[1] = pk2(a[2], a[3]);
  o[2] = pk2(b[0], b[1]); o[3] = pk2(b[2], b[3]);
  *(u32x4*)(dst + i) = o;
}

// ---------------- bf16 GEMM: C[M][N] = A[M][K] @ B[N][K]^T ----------------
// m97 structure: 128x128 tile, BK=64, 4 waves, global_load_lds width 16.
template <int OUTF32>
__global__ __launch_bounds__(256) void gemm_bt(const ushort* __restrict__ A,
                                               const ushort* __restrict__ B,
                                               void* __restrict__ Cv,
                                               int M, int N, int K) {
  __shared__ ushort As[128 * 64];
  __shared__ ushort Bs[128 * 64];
  const int t = threadIdx.x;
  const int l = t & 63, lr = l & 15, lg = l >> 4;
  const int w = t >> 6;
  const int row0 = blockIdx.x * 128, col0 = blockIdx.y * 128;
  const int wr = (w >> 1) * 64, wc = (w & 1) * 64;

  f32x4 acc[4][4] = {};

  const int srow = t >> 3, scol = (t & 7) * 8;       // staging: 16B per thread
  const ushort* Ag = A + (size_t)(row0 + srow) * K + scol;
  const ushort* Bg = B + (size_t)(col0 + srow) * K + scol;
  ushort* Asl = &As[srow * 64 + scol];
  ushort* Bsl = &Bs[srow * 64 + scol];

  for (int k0 = 0; k0 < K; k0 += 64) {
    __syncthreads();
#pragma unroll
    for (int i = 0; i < 4; ++i) {
      gl_lds16(Ag + (size_t)(i * 32) * K + k0, Asl + i * 32 * 64);
      gl_lds16(Bg + (size_t)(i * 32) * K + k0, Bsl + i * 32 * 64);
    }
    asm volatile("s_waitcnt vmcnt(0)" ::: "memory");
    __syncthreads();
#pragma unroll
    for (int ks = 0; ks < 2; ++ks) {
      short8 af[4], bf[4];
#pragma unroll
      for (int m = 0; m < 4; ++m)
        af[m] = *(const short8*)&As[(wr + m * 16 + lr) * 64 + ks * 32 + lg * 8];
#pragma unroll
      for (int n = 0; n < 4; ++n)
        bf[n] = *(const short8*)&Bs[(wc + n * 16 + lr) * 64 + ks * 32 + lg * 8];
#pragma unroll
      for (int m = 0; m < 4; ++m)
#pragma unroll
        for (int n = 0; n < 4; ++n)
          acc[m][n] = MFMA16(af[m], bf[n], acc[m][n]);
    }
  }

  const int crow = row0 + wr + lg * 4;
  const int ccol = col0 + wc + lr;
  if (OUTF32) {
    float* C = (float*)Cv;
#pragma unroll
    for (int m = 0; m < 4; ++m)
#pragma unroll
      for (int n = 0; n < 4; ++n)
#pragma unroll
        for (int j = 0; j < 4; ++j)
          C[(size_t)(crow + m * 16 + j) * N + ccol + n * 16] = acc[m][n][j];
  } else {
    ushort* C = (ushort*)Cv;
#pragma unroll
    for (int m = 0; m < 4; ++m)
#pragma unroll
      for (int n = 0; n < 4; ++n)
#pragma unroll
        for (int j = 0; j < 4; ++j)
          C[(size_t)(crow + m * 16 + j) * N + ccol + n * 16] = (ushort)f2bfu(acc[m][n][j]);
  }
}

// ---------------- RMSNorm + RoPE for Q and K ----------------
// One wave per (b,s,head) row; lane i owns d=i and d=i+64 (rotate_half pairs in-lane).
// Q gets SCALE*log2(e) folded in so attention uses exp2 directly.
__global__ __launch_bounds__(256) void qk_norm_rope(
    const ushort* __restrict__ QKVp, const float* __restrict__ cosb,
    const float* __restrict__ sinb, const float* __restrict__ qw,
    const float* __restrict__ kw, ushort* __restrict__ Qa, ushort* __restrict__ Ka) {
  int r = blockIdx.x * 4 + (threadIdx.x >> 6);
  int i = threadIdx.x & 63;
  int b, s, srccol;
  ushort* dst;
  const float* w;
  float scale;
  if (r < 65536) {                       // Q rows: r = (b*2048+s)*16 + h
    b = r >> 15; int rem = r & 32767; s = rem >> 4; int h = rem & 15;
    srccol = h * 128;
    dst = Qa + ((size_t)((b * 16 + h) * 2048 + s)) * 128;
    w = qw;
    scale = 0.08838834764831845f * 1.4426950408889634f;  // HD^-0.5 * log2(e)
  } else {                               // K rows
    int rk = r - 65536;
    b = rk >> 14; int rem = rk & 16383; s = rem >> 3; int kvh = rem & 7;
    srccol = 2048 + kvh * 128;
    dst = Ka + ((size_t)((b * 8 + kvh) * 2048 + s)) * 128;
    w = kw;
    scale = 1.0f;
  }
  const ushort* src = QKVp + ((size_t)(b * 2048 + s)) * 4096 + srccol;
  float x0 = bf2f(src[i]), x1 = bf2f(src[i + 64]);
  float ss = x0 * x0 + x1 * x1;
#pragma unroll
  for (int m = 1; m < 64; m <<= 1) ss += __shfl_xor(ss, m);
  float inv = rsqrtf(ss * (1.0f / 128.0f) + 1e-6f);
  float xn0 = x0 * inv * w[i], xn1 = x1 * inv * w[i + 64];
  const float* cp = cosb + ((size_t)(b * 2048 + s)) * 128;
  const float* sp = sinb + ((size_t)(b * 2048 + s)) * 128;
  float o0 = (xn0 * cp[i] - xn1 * sp[i]) * scale;
  float o1 = (xn1 * cp[i + 64] + xn0 * sp[i + 64]) * scale;
  dst[i] = (ushort)f2bfu(o0);
  dst[i + 64] = (ushort)f2bfu(o1);
}

// ---------------- V transpose: QKVp[.,3072+kvh*128+d] -> Vt[b][kvh][d][s] ----------------
__global__ __launch_bounds__(256) void v_transpose(const ushort* __restrict__ QKVp,
                                                   ushort* __restrict__ Vt) {
  __shared__ ushort tile[64][136];       // 136 keeps 16B alignment per row
  int blk = blockIdx.x;
  int st = blk & 31, kvh = (blk >> 5) & 7, b = blk >> 8;
  int t = threadIdx.x;
  int s0 = st * 64;
  {
    int r = t >> 2, cseg = (t & 3) * 32;
    const ushort* src = QKVp + ((size_t)(b * 2048 + s0 + r)) * 4096 + 3072 + kvh * 128 + cseg;
#pragma unroll
    for (int i = 0; i < 4; ++i)
      *(uint4*)&tile[r][cseg + i * 8] = *(const uint4*)(src + i * 8);
  }
  __syncthreads();
  {
    int d = t >> 1, sh = (t & 1) * 32;
    ushort* dst = Vt + ((size_t)((b * 8 + kvh) * 128 + d)) * 2048 + s0 + sh;
    ushort buf[32];
#pragma unroll
    for (int k = 0; k < 32; ++k) buf[k] = tile[sh + k][d];
#pragma unroll
    for (int i = 0; i < 4; ++i) *(uint4*)(dst + i * 8) = *(uint4*)&buf[i * 8];
  }
}

// ---------------- Flash attention (non-causal, GQA 2:1) ----------------
// 4 waves/block, each wave owns 32 q-rows. Swapped QK^T (S^T = K x Q^T) so the
// softmax reduce is regs + shfl_xor(16/32). P -> LDS roundtrip into B-frag layout.
__global__ __launch_bounds__(256) void attn_kernel(const ushort* __restrict__ Qa,
                                                   const ushort* __restrict__ Ka,
                                                   const ushort* __restrict__ Vt,
                                                   ushort* __restrict__ Ctx) {
  __shared__ ushort Plds[4][2][16][32];  // [wave][qt][q][k]
  const int bh = blockIdx.x, b = bh >> 4, h = bh & 15, kvh = h >> 1;
  const int t = threadIdx.x, w = t >> 6, l = t & 63, lr = l & 15, lg = l >> 4;
  const int q0 = blockIdx.y * 128 + w * 32;
  const ushort* Qh = Qa + ((size_t)(b * 16 + h)) * 2048 * 128;
  const ushort* Kh = Ka + ((size_t)(b * 8 + kvh)) * 2048 * 128;
  const ushort* Vh = Vt + ((size_t)(b * 8 + kvh)) * 128 * 2048;

  short8 bq[2][4];
#pragma unroll
  for (int qt = 0; qt < 2; ++qt)
#pragma unroll
    for (int dc = 0; dc < 4; ++dc)
      bq[qt][dc] = *(const short8*)&Qh[(size_t)(q0 + qt * 16 + lr) * 128 + dc * 32 + lg * 8];

  f32x4 accO[8][2] = {};
  float mrun[2] = {-3.0e38f, -3.0e38f};
  float lrun[2] = {0.f, 0.f};

  for (int kt0 = 0; kt0 < 2048; kt0 += 32) {
    f32x4 accS[2][2] = {};   // [kts][qt], S^T tiles (rows=k, cols=q)
#pragma unroll
    for (int dc = 0; dc < 4; ++dc) {
      short8 ak0 = *(const short8*)&Kh[(size_t)(kt0 + lr) * 128 + dc * 32 + lg * 8];
      short8 ak1 = *(const short8*)&Kh[(size_t)(kt0 + 16 + lr) * 128 + dc * 32 + lg * 8];
#pragma unroll
      for (int qt = 0; qt < 2; ++qt) {
        accS[0][qt] = MFMA16(ak0, bq[qt][dc], accS[0][qt]);
        accS[1][qt] = MFMA16(ak1, bq[qt][dc], accS[1][qt]);
      }
    }
#pragma unroll
    for (int qt = 0; qt < 2; ++qt) {
      float tm = accS[0][qt][0];
#pragma unroll
      for (int j = 1; j < 4; ++j) tm = fmaxf(tm, accS[0][qt][j]);
#pragma unroll
      for (int j = 0; j < 4; ++j) tm = fmaxf(tm, accS[1][qt][j]);
      tm = fmaxf(tm, __shfl_xor(tm, 16));
      tm = fmaxf(tm, __shfl_xor(tm, 32));
      float nm = fmaxf(mrun[qt], tm);
      float cf = exp2f(mrun[qt] - nm);
      float ts = 0.f;
#pragma unroll
      for (int kts = 0; kts < 2; ++kts)
#pragma unroll
        for (int j = 0; j < 4; ++j) {
          float p = exp2f(accS[kts][qt][j] - nm);
          accS[kts][qt][j] = p;
          ts += p;
        }
      ts += __shfl_xor(ts, 16);
      ts += __shfl_xor(ts, 32);
      lrun[qt] = lrun[qt] * cf + ts;
      mrun[qt] = nm;
#pragma unroll
      for (int dc = 0; dc < 8; ++dc) {
        accO[dc][qt][0] *= cf; accO[dc][qt][1] *= cf;
        accO[dc][qt][2] *= cf; accO[dc][qt][3] *= cf;
      }
#pragma unroll
      for (int kts = 0; kts < 2; ++kts) {
        u32x2 pv;
        pv[0] = pk2(accS[kts][qt][0], accS[kts][qt][1]);
        pv[1] = pk2(accS[kts][qt][2], accS[kts][qt][3]);
        *(u32x2*)&Plds[w][qt][lr][kts * 16 + lg * 4] = pv;
      }
    }
    asm volatile("s_waitcnt lgkmcnt(0)" ::: "memory");
    short8 bp[2];
#pragma unroll
    for (int qt = 0; qt < 2; ++qt)
      bp[qt] = *(const short8*)&Plds[w][qt][lr][lg * 8];
#pragma unroll
    for (int dc = 0; dc < 8; ++dc) {
      short8 av = *(const short8*)&Vh[(size_t)(dc * 16 + lr) * 2048 + kt0 + lg * 8];
#pragma unroll
      for (int qt = 0; qt < 2; ++qt)
        accO[dc][qt] = MFMA16(av, bp[qt], accO[dc][qt]);
    }
  }

#pragma unroll
  for (int qt = 0; qt < 2; ++qt) {
    float inv = 1.0f / lrun[qt];
    int srow = q0 + qt * 16 + lr;
#pragma unroll
    for (int dc = 0; dc < 8; ++dc) {
      u32x2 ov;
      ov[0] = pk2(accO[dc][qt][0] * inv, accO[dc][qt][1] * inv);
      ov[1] = pk2(accO[dc][qt][2] * inv, accO[dc][qt][3] * inv);
      *(u32x2*)&Ctx[(size_t)(b * 2048 + srow) * 2048 + h * 128 + dc * 16 + lg * 4] = ov;
    }
  }
}

// ---------------- host ----------------
extern "C" void kernel_launch(void* const* d_in, const int* in_sizes, int n_in,
                              void* d_out, int out_size, void* d_ws, size_t ws_size,
                              hipStream_t stream) {
  const float* hidden = (const float*)d_in[0];
  const float* cosb   = (const float*)d_in[1];
  const float* sinb   = (const float*)d_in[2];
  const float* Wq     = (const float*)d_in[3];
  const float* Wk     = (const float*)d_in[4];
  const float* Wv     = (const float*)d_in[5];
  const float* Wo     = (const float*)d_in[6];
  const float* qw     = (const float*)d_in[7];
  const float* kw     = (const float*)d_in[8];

  char* ws = (char*)d_ws;
  ushort* Xb    = (ushort*)ws; ws += (size_t)4096 * 2048 * 2;
  ushort* Wcomb = (ushort*)ws; ws += (size_t)4096 * 2048 * 2;
  ushort* Wob   = (ushort*)ws; ws += (size_t)2048 * 2048 * 2;
  ushort* QKVp  = (ushort*)ws; ws += (size_t)4096 * 4096 * 2;
  ushort* Qa    = (ushort*)ws; ws += (size_t)2 * 16 * 2048 * 128 * 2;
  ushort* Ka    = (ushort*)ws; ws += (size_t)2 * 8 * 2048 * 128 * 2;
  ushort* Vt    = (ushort*)ws; ws += (size_t)2 * 8 * 2048 * 128 * 2;
  ushort* Ctx   = (ushort*)ws; ws += (size_t)4096 * 2048 * 2;

  f2b8<<<4096, 256, 0, stream>>>(hidden, Xb, 8388608);
  f2b8<<<2048, 256, 0, stream>>>(Wq, Wcomb, 4194304);
  f2b8<<<1024, 256, 0, stream>>>(Wk, Wcomb + 4194304, 2097152);
  f2b8<<<1024, 256, 0, stream>>>(Wv, Wcomb + 6291456, 2097152);
  f2b8<<<2048, 256, 0, stream>>>(Wo, Wob, 4194304);

  gemm_bt<0><<<dim3(32, 32), 256, 0, stream>>>(Xb, Wcomb, (void*)QKVp, 4096, 4096, 2048);

  qk_norm_rope<<<24576, 256, 0, stream>>>(QKVp, cosb, sinb, qw, kw, Qa, Ka);
  v_transpose<<<512, 256, 0, stream>>>(QKVp, Vt);

  attn_kernel<<<dim3(32, 16), 256, 0, stream>>>(Qa, Ka, Vt, Ctx);

  gemm_bt<1><<<dim3(32, 16), 256, 0, stream>>>(Ctx, Wob, d_out, 4096, 2048, 2048);
}

// Round 2
// 422.532 us; speedup vs baseline: 1.3051x; 1.3051x over previous
//
#include <hip/hip_runtime.h>

using short8 = __attribute__((ext_vector_type(8))) short;
using f32x4  = __attribute__((ext_vector_type(4))) float;
using u32x2  = __attribute__((ext_vector_type(2))) unsigned int;
using u32x4  = __attribute__((ext_vector_type(4))) unsigned int;

#define MFMA16(a, b, c) __builtin_amdgcn_mfma_f32_16x16x32_bf16((a), (b), (c), 0, 0, 0)

__device__ inline float bf2f(ushort v) { return __uint_as_float(((unsigned int)v) << 16); }
__device__ inline unsigned int f2bfu(float f) {
  unsigned int u = __float_as_uint(f);
  return (u + 0x7fffu + ((u >> 16) & 1u)) >> 16;   // RNE
}
__device__ inline unsigned int pk2(float a, float b) { return f2bfu(a) | (f2bfu(b) << 16); }

__device__ inline void gl_lds16(const ushort* g, ushort* l) {
  __builtin_amdgcn_global_load_lds(
      (const __attribute__((address_space(1))) void*)g,
      (__attribute__((address_space(3))) void*)l, 16, 0, 0);
}

// ---------------- fp32 -> bf16 convert, 8 elems/thread ----------------
__global__ __launch_bounds__(256) void f2b8(const float* __restrict__ src,
                                            ushort* __restrict__ dst, int n) {
  int i = (blockIdx.x * 256 + threadIdx.x) * 8;
  if (i >= n) return;
  f32x4 a = *(const f32x4*)(src + i);
  f32x4 b = *(const f32x4*)(src + i + 4);
  u32x4 o;
  o[0] = pk2(a[0], a[1]); o[1] = pk2(a[2], a[3]);
  o[2] = pk2(b[0], b[1]); o[3] = pk2(b[2], b[3]);
  *(u32x4*)(dst + i) = o;
}

// ---------------- bf16 GEMM: C[M][N] = A[M][K] @ B[N][K]^T ----------------
template <int OUTF32>
__global__ __launch_bounds__(256) void gemm_bt(const ushort* __restrict__ A,
                                               const ushort* __restrict__ B,
                                               void* __restrict__ Cv,
                                               int M, int N, int K) {
  __shared__ ushort As[128 * 64];
  __shared__ ushort Bs[128 * 64];
  const int t = threadIdx.x;
  const int l = t & 63, lr = l & 15, lg = l >> 4;
  const int w = t >> 6;
  const int row0 = blockIdx.x * 128, col0 = blockIdx.y * 128;
  const int wr = (w >> 1) * 64, wc = (w & 1) * 64;

  f32x4 acc[4][4] = {};

  const int srow = t >> 3, scol = (t & 7) * 8;
  const ushort* Ag = A + (size_t)(row0 + srow) * K + scol;
  const ushort* Bg = B + (size_t)(col0 + srow) * K + scol;
  ushort* Asl = &As[srow * 64 + scol];
  ushort* Bsl = &Bs[srow * 64 + scol];

  for (int k0 = 0; k0 < K; k0 += 64) {
    __syncthreads();
#pragma unroll
    for (int i = 0; i < 4; ++i) {
      gl_lds16(Ag + (size_t)(i * 32) * K + k0, Asl + i * 32 * 64);
      gl_lds16(Bg + (size_t)(i * 32) * K + k0, Bsl + i * 32 * 64);
    }
    asm volatile("s_waitcnt vmcnt(0)" ::: "memory");
    __syncthreads();
#pragma unroll
    for (int ks = 0; ks < 2; ++ks) {
      short8 af[4], bf[4];
#pragma unroll
      for (int m = 0; m < 4; ++m)
        af[m] = *(const short8*)&As[(wr + m * 16 + lr) * 64 + ks * 32 + lg * 8];
#pragma unroll
      for (int n = 0; n < 4; ++n)
        bf[n] = *(const short8*)&Bs[(wc + n * 16 + lr) * 64 + ks * 32 + lg * 8];
#pragma unroll
      for (int m = 0; m < 4; ++m)
#pragma unroll
        for (int n = 0; n < 4; ++n)
          acc[m][n] = MFMA16(af[m], bf[n], acc[m][n]);
    }
  }

  const int crow = row0 + wr + lg * 4;
  const int ccol = col0 + wc + lr;
  if (OUTF32) {
    float* C = (float*)Cv;
#pragma unroll
    for (int m = 0; m < 4; ++m)
#pragma unroll
      for (int n = 0; n < 4; ++n)
#pragma unroll
        for (int j = 0; j < 4; ++j)
          C[(size_t)(crow + m * 16 + j) * N + ccol + n * 16] = acc[m][n][j];
  } else {
    ushort* C = (ushort*)Cv;
#pragma unroll
    for (int m = 0; m < 4; ++m)
#pragma unroll
      for (int n = 0; n < 4; ++n)
#pragma unroll
        for (int j = 0; j < 4; ++j)
          C[(size_t)(crow + m * 16 + j) * N + ccol + n * 16] = (ushort)f2bfu(acc[m][n][j]);
  }
}

// ---------------- RMSNorm + RoPE for Q and K ----------------
__global__ __launch_bounds__(256) void qk_norm_rope(
    const ushort* __restrict__ QKVp, const float* __restrict__ cosb,
    const float* __restrict__ sinb, const float* __restrict__ qw,
    const float* __restrict__ kw, ushort* __restrict__ Qa, ushort* __restrict__ Ka) {
  int r = blockIdx.x * 4 + (threadIdx.x >> 6);
  int i = threadIdx.x & 63;
  int b, s, srccol;
  ushort* dst;
  const float* w;
  float scale;
  if (r < 65536) {                       // Q rows
    b = r >> 15; int rem = r & 32767; s = rem >> 4; int h = rem & 15;
    srccol = h * 128;
    dst = Qa + ((size_t)((b * 16 + h) * 2048 + s)) * 128;
    w = qw;
    scale = 0.08838834764831845f * 1.4426950408889634f;  // HD^-0.5 * log2(e)
  } else {                               // K rows
    int rk = r - 65536;
    b = rk >> 14; int rem = rk & 16383; s = rem >> 3; int kvh = rem & 7;
    srccol = 2048 + kvh * 128;
    dst = Ka + ((size_t)((b * 8 + kvh) * 2048 + s)) * 128;
    w = kw;
    scale = 1.0f;
  }
  const ushort* src = QKVp + ((size_t)(b * 2048 + s)) * 4096 + srccol;
  float x0 = bf2f(src[i]), x1 = bf2f(src[i + 64]);
  float ss = x0 * x0 + x1 * x1;
#pragma unroll
  for (int m = 1; m < 64; m <<= 1) ss += __shfl_xor(ss, m);
  float inv = rsqrtf(ss * (1.0f / 128.0f) + 1e-6f);
  float xn0 = x0 * inv * w[i], xn1 = x1 * inv * w[i + 64];
  const float* cp = cosb + ((size_t)(b * 2048 + s)) * 128;
  const float* sp = sinb + ((size_t)(b * 2048 + s)) * 128;
  float o0 = (xn0 * cp[i] - xn1 * sp[i]) * scale;
  float o1 = (xn1 * cp[i + 64] + xn0 * sp[i + 64]) * scale;
  dst[i] = (ushort)f2bfu(o0);
  dst[i + 64] = (ushort)f2bfu(o1);
}

// ---------------- V transpose -> Vt[b][kvh][d][s] ----------------
__global__ __launch_bounds__(256) void v_transpose(const ushort* __restrict__ QKVp,
                                                   ushort* __restrict__ Vt) {
  __shared__ ushort tile[64][136];
  int blk = blockIdx.x;
  int st = blk & 31, kvh = (blk >> 5) & 7, b = blk >> 8;
  int t = threadIdx.x;
  int s0 = st * 64;
  {
    int r = t >> 2, cseg = (t & 3) * 32;
    const ushort* src = QKVp + ((size_t)(b * 2048 + s0 + r)) * 4096 + 3072 + kvh * 128 + cseg;
#pragma unroll
    for (int i = 0; i < 4; ++i)
      *(uint4*)&tile[r][cseg + i * 8] = *(const uint4*)(src + i * 8);
  }
  __syncthreads();
  {
    int d = t >> 1, sh = (t & 1) * 32;
    ushort* dst = Vt + ((size_t)((b * 8 + kvh) * 128 + d)) * 2048 + s0 + sh;
    ushort buf[32];
#pragma unroll
    for (int k = 0; k < 32; ++k) buf[k] = tile[sh + k][d];
#pragma unroll
    for (int i = 0; i < 4; ++i) *(uint4*)(dst + i * 8) = *(uint4*)&buf[i * 8];
  }
}

// ---------------- Flash attention v2 ----------------
// 4 waves x 32 q-rows = 128 q/block. KVBLK=64. K,V staged once per block in
// swizzled LDS (pre-swizzled global source, rule #21). Defer-rescale (T13).
__global__ __launch_bounds__(256, 2) void attn_kernel(const ushort* __restrict__ Qa,
                                                      const ushort* __restrict__ Ka,
                                                      const ushort* __restrict__ Vt,
                                                      ushort* __restrict__ Ctx) {
  __shared__ ushort Ks[64 * 128];   // [k-row][d], 16B-slot ^= (row&7)
  __shared__ ushort Vs[128 * 64];   // [d-row][k], 16B-slot ^= (row&7)
  __shared__ ushort Ps[8 * 1024];   // per (wave,qt): [q-row][k], slot ^= (row&7)
  const int bh = blockIdx.x, b = bh >> 4, h = bh & 15, kvh = h >> 1;
  const int t = threadIdx.x, w = t >> 6, l = t & 63, lr = l & 15, lg = l >> 4;
  const int q0 = blockIdx.y * 128 + w * 32;
  const ushort* Qh = Qa + ((size_t)(b * 16 + h)) * 2048 * 128;
  const ushort* Kh = Ka + ((size_t)(b * 8 + kvh)) * 2048 * 128;
  const ushort* Vh = Vt + ((size_t)(b * 8 + kvh)) * 128 * 2048;

  short8 bq[2][4];
#pragma unroll
  for (int qt = 0; qt < 2; ++qt)
#pragma unroll
    for (int dc = 0; dc < 4; ++dc)
      bq[qt][dc] = *(const short8*)&Qh[(size_t)(q0 + qt * 16 + lr) * 128 + dc * 32 + lg * 8];

  f32x4 accO[8][2] = {};
  float mrun[2] = {-3.0e38f, -3.0e38f};
  float lrun[2] = {0.f, 0.f};

  for (int kt0 = 0; kt0 < 2048; kt0 += 64) {
    __syncthreads();
#pragma unroll
    for (int i = 0; i < 4; ++i) {
      const int c = w * 4 + i;
      const int krow = c * 4 + lg;                 // K tile row this lane stages
      gl_lds16(Kh + (size_t)(kt0 + krow) * 128 + (((l & 15) ^ (krow & 7)) * 8),
               &Ks[c * 512]);
      const int vrow = c * 8 + (l >> 3);           // V tile row this lane stages
      gl_lds16(Vh + (size_t)vrow * 2048 + kt0 + (((l & 7) ^ ((l >> 3) & 7)) * 8),
               &Vs[c * 512]);
    }
    asm volatile("s_waitcnt vmcnt(0)" ::: "memory");
    __syncthreads();

    // ---- QK^T (S^T: rows=k, cols=q) ----
    f32x4 accS[4][2] = {};
#pragma unroll
    for (int dc = 0; dc < 4; ++dc) {
      short8 ak[4];
#pragma unroll
      for (int kts = 0; kts < 4; ++kts)
        ak[kts] = *(const short8*)&Ks[(kts * 16 + lr) * 128 + ((dc * 4 + lg) ^ (lr & 7)) * 8];
#pragma unroll
      for (int kts = 0; kts < 4; ++kts)
#pragma unroll
        for (int qt = 0; qt < 2; ++qt)
          accS[kts][qt] = MFMA16(ak[kts], bq[qt][dc], accS[kts][qt]);
    }

    // ---- online softmax (per q-column, reduce over lg via shfl) ----
#pragma unroll
    for (int qt = 0; qt < 2; ++qt) {
      float m0 = fmaxf(fmaxf(accS[0][qt][0], accS[0][qt][1]), fmaxf(accS[0][qt][2], accS[0][qt][3]));
      float m1 = fmaxf(fmaxf(accS[1][qt][0], accS[1][qt][1]), fmaxf(accS[1][qt][2], accS[1][qt][3]));
      float m2 = fmaxf(fmaxf(accS[2][qt][0], accS[2][qt][1]), fmaxf(accS[2][qt][2], accS[2][qt][3]));
      float m3 = fmaxf(fmaxf(accS[3][qt][0], accS[3][qt][1]), fmaxf(accS[3][qt][2], accS[3][qt][3]));
      float tm = fmaxf(fmaxf(m0, m1), fmaxf(m2, m3));
      tm = fmaxf(tm, __shfl_xor(tm, 16));
      tm = fmaxf(tm, __shfl_xor(tm, 32));
      if (!__all(tm <= mrun[qt] + 11.0f)) {        // T13 defer-rescale
        float nm = fmaxf(mrun[qt], tm);
        float cf = exp2f(mrun[qt] - nm);
#pragma unroll
        for (int dc = 0; dc < 8; ++dc) {
          accO[dc][qt][0] *= cf; accO[dc][qt][1] *= cf;
          accO[dc][qt][2] *= cf; accO[dc][qt][3] *= cf;
        }
        lrun[qt] *= cf;
        mrun[qt] = nm;
      }
      float ts = 0.f;
#pragma unroll
      for (int kts = 0; kts < 4; ++kts)
#pragma unroll
        for (int j = 0; j < 4; ++j) {
          float p = exp2f(accS[kts][qt][j] - mrun[qt]);
          accS[kts][qt][j] = p;
          ts += p;
        }
      ts += __shfl_xor(ts, 16);
      ts += __shfl_xor(ts, 32);
      lrun[qt] += ts;
#pragma unroll
      for (int kts = 0; kts < 4; ++kts) {
        u32x2 pv;
        pv[0] = pk2(accS[kts][qt][0], accS[kts][qt][1]);
        pv[1] = pk2(accS[kts][qt][2], accS[kts][qt][3]);
        *(u32x2*)&Ps[(w * 2 + qt) * 1024 + lr * 64 +
                     (((kts * 2 + (lg >> 1)) ^ (lr & 7)) * 8 + (lg & 1) * 4)] = pv;
      }
    }
    asm volatile("s_waitcnt lgkmcnt(0)" ::: "memory");

    // ---- PV ----
    short8 bp[2][2];
#pragma unroll
    for (int qt = 0; qt < 2; ++qt)
#pragma unroll
      for (int ks = 0; ks < 2; ++ks)
        bp[qt][ks] = *(const short8*)&Ps[(w * 2 + qt) * 1024 + lr * 64 +
                                         ((ks * 4 + lg) ^ (lr & 7)) * 8];
#pragma unroll
    for (int dc = 0; dc < 8; ++dc) {
      short8 av[2];
#pragma unroll
      for (int ks = 0; ks < 2; ++ks)
        av[ks] = *(const short8*)&Vs[(dc * 16 + lr) * 64 + ((ks * 4 + lg) ^ (lr & 7)) * 8];
#pragma unroll
      for (int ks = 0; ks < 2; ++ks)
#pragma unroll
        for (int qt = 0; qt < 2; ++qt)
          accO[dc][qt] = MFMA16(av[ks], bp[qt][ks], accO[dc][qt]);
    }
  }

#pragma unroll
  for (int qt = 0; qt < 2; ++qt) {
    float inv = 1.0f / lrun[qt];
    int srow = q0 + qt * 16 + lr;
#pragma unroll
    for (int dc = 0; dc < 8; ++dc) {
      u32x2 ov;
      ov[0] = pk2(accO[dc][qt][0] * inv, accO[dc][qt][1] * inv);
      ov[1] = pk2(accO[dc][qt][2] * inv, accO[dc][qt][3] * inv);
      *(u32x2*)&Ctx[(size_t)(b * 2048 + srow) * 2048 + h * 128 + dc * 16 + lg * 4] = ov;
    }
  }
}

// ---------------- host ----------------
extern "C" void kernel_launch(void* const* d_in, const int* in_sizes, int n_in,
                              void* d_out, int out_size, void* d_ws, size_t ws_size,
                              hipStream_t stream) {
  const float* hidden = (const float*)d_in[0];
  const float* cosb   = (const float*)d_in[1];
  const float* sinb   = (const float*)d_in[2];
  const float* Wq     = (const float*)d_in[3];
  const float* Wk     = (const float*)d_in[4];
  const float* Wv     = (const float*)d_in[5];
  const float* Wo     = (const float*)d_in[6];
  const float* qw     = (const float*)d_in[7];
  const float* kw     = (const float*)d_in[8];

  char* ws = (char*)d_ws;
  ushort* Xb    = (ushort*)ws; ws += (size_t)4096 * 2048 * 2;
  ushort* Wcomb = (ushort*)ws; ws += (size_t)4096 * 2048 * 2;
  ushort* Wob   = (ushort*)ws; ws += (size_t)2048 * 2048 * 2;
  ushort* QKVp  = (ushort*)ws; ws += (size_t)4096 * 4096 * 2;
  ushort* Qa    = (ushort*)ws; ws += (size_t)2 * 16 * 2048 * 128 * 2;
  ushort* Ka    = (ushort*)ws; ws += (size_t)2 * 8 * 2048 * 128 * 2;
  ushort* Vt    = (ushort*)ws; ws += (size_t)2 * 8 * 2048 * 128 * 2;
  ushort* Ctx   = (ushort*)ws; ws += (size_t)4096 * 2048 * 2;

  f2b8<<<4096, 256, 0, stream>>>(hidden, Xb, 8388608);
  f2b8<<<2048, 256, 0, stream>>>(Wq, Wcomb, 4194304);
  f2b8<<<1024, 256, 0, stream>>>(Wk, Wcomb + 4194304, 2097152);
  f2b8<<<1024, 256, 0, stream>>>(Wv, Wcomb + 6291456, 2097152);
  f2b8<<<2048, 256, 0, stream>>>(Wo, Wob, 4194304);

  gemm_bt<0><<<dim3(32, 32), 256, 0, stream>>>(Xb, Wcomb, (void*)QKVp, 4096, 4096, 2048);

  qk_norm_rope<<<24576, 256, 0, stream>>>(QKVp, cosb, sinb, qw, kw, Qa, Ka);
  v_transpose<<<512, 256, 0, stream>>>(QKVp, Vt);

  attn_kernel<<<dim3(32, 16), 256, 0, stream>>>(Qa, Ka, Vt, Ctx);

  gemm_bt<1><<<dim3(32, 16), 256, 0, stream>>>(Ctx, Wob, d_out, 4096, 2048, 2048);
}

// Round 3
// 379.125 us; speedup vs baseline: 1.4545x; 1.1145x over previous
//
#include <hip/hip_runtime.h>

using short8 = __attribute__((ext_vector_type(8))) short;
using f32x4  = __attribute__((ext_vector_type(4))) float;
using u32x2  = __attribute__((ext_vector_type(2))) unsigned int;
using u32x4  = __attribute__((ext_vector_type(4))) unsigned int;

#define MFMA16(a, b, c) __builtin_amdgcn_mfma_f32_16x16x32_bf16((a), (b), (c), 0, 0, 0)

__device__ inline float bf2f(ushort v) { return __uint_as_float(((unsigned int)v) << 16); }
__device__ inline unsigned int f2bfu(float f) {
  unsigned int u = __float_as_uint(f);
  return (u + 0x7fffu + ((u >> 16) & 1u)) >> 16;   // RNE
}
__device__ inline unsigned int pk2(float a, float b) { return f2bfu(a) | (f2bfu(b) << 16); }

__device__ inline void gl_lds16(const ushort* g, ushort* l) {
  __builtin_amdgcn_global_load_lds(
      (const __attribute__((address_space(1))) void*)g,
      (__attribute__((address_space(3))) void*)l, 16, 0, 0);
}

// ---------------- fp32 -> bf16 convert, 8 elems/thread ----------------
__global__ __launch_bounds__(256) void f2b8(const float* __restrict__ src,
                                            ushort* __restrict__ dst, int n) {
  int i = (blockIdx.x * 256 + threadIdx.x) * 8;
  if (i >= n) return;
  f32x4 a = *(const f32x4*)(src + i);
  f32x4 b = *(const f32x4*)(src + i + 4);
  u32x4 o;
  o[0] = pk2(a[0], a[1]); o[1] = pk2(a[2], a[3]);
  o[2] = pk2(b[0], b[1]); o[3] = pk2(b[2], b[3]);
  *(u32x4*)(dst + i) = o;
}

// ---------------- 256x256 8-phase bf16 GEMM: C = A[M][K] @ B[N][K]^T ----------------
// 8 waves (2M x 4N), BK=64, 2 K-tiles per iteration, 8 phases, counted vmcnt(4),
// XOR slot-swizzle (slot ^= row&7) via pre-swizzled global source, setprio on MFMA.
// LDS map (ushort idx): buf c at c*32768; A-half h at h*8192; B-half h at 16384+h*8192.
#define GPHASE(CB, P, STG, VMW)                                                     \
  {                                                                                 \
    if (P == 0) {                                                                   \
      _Pragma("unroll") for (int n = 0; n < 4; ++n) {                               \
        bf[n][0] = *(const short8*)&L[(CB)*32768 + bBase + n*1024 + rdoff];         \
        bf[n][1] = *(const short8*)&L[(CB)*32768 + bBase + n*1024 + (rdoff ^ 32)];  \
      }                                                                             \
    }                                                                               \
    short8 af[2][2];                                                                \
    _Pragma("unroll") for (int mi = 0; mi < 2; ++mi) {                              \
      af[mi][0] = *(const short8*)&L[(CB)*32768 + aBase + ((P)*2+mi)*1024 + rdoff];        \
      af[mi][1] = *(const short8*)&L[(CB)*32768 + aBase + ((P)*2+mi)*1024 + (rdoff ^ 32)]; \
    }                                                                               \
    STG;                                                                            \
    __builtin_amdgcn_s_barrier();                                                   \
    asm volatile("s_waitcnt lgkmcnt(0)" ::: "memory");                              \
    __builtin_amdgcn_s_setprio(1);                                                  \
    _Pragma("unroll") for (int mi = 0; mi < 2; ++mi)                                \
      _Pragma("unroll") for (int n = 0; n < 4; ++n) {                               \
        acc[(P)*2+mi][n] = MFMA16(af[mi][0], bf[n][0], acc[(P)*2+mi][n]);           \
        acc[(P)*2+mi][n] = MFMA16(af[mi][1], bf[n][1], acc[(P)*2+mi][n]);           \
      }                                                                             \
    __builtin_amdgcn_s_setprio(0);                                                  \
    VMW;                                                                            \
    __builtin_amdgcn_s_barrier();                                                   \
  }

#define VM4 asm volatile("s_waitcnt vmcnt(4)" ::: "memory")
#define NOPX (void)0

template <int OUTF32>
__global__ __launch_bounds__(512, 2) void gemm256(const ushort* __restrict__ A,
                                                  const ushort* __restrict__ B,
                                                  void* __restrict__ Cv,
                                                  int M, int N, int K) {
  __shared__ ushort L[65536];  // 128 KiB
  const int t = threadIdx.x;
  const int w = t >> 6, l = t & 63, lr = l & 15, lg = l >> 4;
  const int wr = w >> 2, wc = w & 3;                 // 2 x 4 wave grid
  const int m0 = blockIdx.x * 256, n0 = blockIdx.y * 256;
  const int NT = K >> 6, NI = NT >> 1;

  f32x4 acc[8][4] = {};

  // read-side offsets (ushort units): row lr, slot (lg ^ (lr&7)); ks flips bit2 of slot (^32)
  const int rdoff = lr * 64 + ((lg ^ (lr & 7)) * 8);
  const int aBase = wr * 8192;                        // this wave's A half
  const int bBase = 16384 + (wc >> 1) * 8192 + (wc & 1) * 4096;  // this wave's B half+64-row block

  // staging: wave w owns chunks 2w, 2w+1 (8 rows each); lane l -> row chunk*8+(l>>3),
  // source col-slot (l&7)^(l>>3) so linear LDS holds swizzled content (rule #21)
  const int ch0 = w * 2, ch1 = w * 2 + 1;
  const int srow0 = ch0 * 8 + (l >> 3), srow1 = ch1 * 8 + (l >> 3);
  const int scol = ((l & 7) ^ (l >> 3)) * 8;

  auto stage_a = [&](int h, int kt, int cb) {
    int ktc = kt < NT ? kt : NT - 1;
    gl_lds16(A + (size_t)(m0 + h * 128 + srow0) * K + ktc * 64 + scol,
             (ushort*)&L[cb * 32768 + h * 8192 + ch0 * 512]);
    gl_lds16(A + (size_t)(m0 + h * 128 + srow1) * K + ktc * 64 + scol,
             (ushort*)&L[cb * 32768 + h * 8192 + ch1 * 512]);
  };
  auto stage_b = [&](int h, int kt, int cb) {
    int ktc = kt < NT ? kt : NT - 1;
    gl_lds16(B + (size_t)(n0 + h * 128 + srow0) * K + ktc * 64 + scol,
             (ushort*)&L[cb * 32768 + 16384 + h * 8192 + ch0 * 512]);
    gl_lds16(B + (size_t)(n0 + h * 128 + srow1) * K + ktc * 64 + scol,
             (ushort*)&L[cb * 32768 + 16384 + h * 8192 + ch1 * 512]);
  };

  // prologue: tile0 full -> buf0, tile1 B -> buf1; wait all of tile0 (allow 2 half-tiles out)
  stage_a(0, 0, 0); stage_a(1, 0, 0); stage_b(0, 0, 0); stage_b(1, 0, 0);
  stage_b(0, 1, 1); stage_b(1, 1, 1);
  VM4;
  __builtin_amdgcn_s_barrier();

  short8 bf[4][2];
  for (int I = 0; I < NI; ++I) {
    const int t1 = 2 * I + 1, t2 = 2 * I + 2, t3 = 2 * I + 3;
    GPHASE(0, 0, stage_a(0, t1, 1), NOPX)
    GPHASE(0, 1, stage_a(1, t1, 1), NOPX)
    GPHASE(0, 2, stage_b(0, t2, 0), NOPX)
    GPHASE(0, 3, stage_b(1, t2, 0), VM4)
    GPHASE(1, 0, stage_a(0, t2, 0), NOPX)
    GPHASE(1, 1, stage_a(1, t2, 0), NOPX)
    GPHASE(1, 2, stage_b(0, t3, 1), NOPX)
    GPHASE(1, 3, stage_b(1, t3, 1), VM4)
  }

  const int crow0 = m0 + wr * 128 + lg * 4;
  const int ccol = n0 + wc * 64 + lr;
  if (OUTF32) {
    float* C = (float*)Cv;
#pragma unroll
    for (int m = 0; m < 8; ++m)
#pragma unroll
      for (int n = 0; n < 4; ++n)
#pragma unroll
        for (int j = 0; j < 4; ++j)
          C[(size_t)(crow0 + m * 16 + j) * N + ccol + n * 16] = acc[m][n][j];
  } else {
    ushort* C = (ushort*)Cv;
#pragma unroll
    for (int m = 0; m < 8; ++m)
#pragma unroll
      for (int n = 0; n < 4; ++n)
#pragma unroll
        for (int j = 0; j < 4; ++j)
          C[(size_t)(crow0 + m * 16 + j) * N + ccol + n * 16] = (ushort)f2bfu(acc[m][n][j]);
  }
}

// ---------------- RMSNorm + RoPE for Q and K ----------------
__global__ __launch_bounds__(256) void qk_norm_rope(
    const ushort* __restrict__ QKVp, const float* __restrict__ cosb,
    const float* __restrict__ sinb, const float* __restrict__ qw,
    const float* __restrict__ kw, ushort* __restrict__ Qa, ushort* __restrict__ Ka) {
  int r = blockIdx.x * 4 + (threadIdx.x >> 6);
  int i = threadIdx.x & 63;
  int b, s, srccol;
  ushort* dst;
  const float* w;
  float scale;
  if (r < 65536) {                       // Q rows
    b = r >> 15; int rem = r & 32767; s = rem >> 4; int h = rem & 15;
    srccol = h * 128;
    dst = Qa + ((size_t)((b * 16 + h) * 2048 + s)) * 128;
    w = qw;
    scale = 0.08838834764831845f * 1.4426950408889634f;  // HD^-0.5 * log2(e)
  } else {                               // K rows
    int rk = r - 65536;
    b = rk >> 14; int rem = rk & 16383; s = rem >> 3; int kvh = rem & 7;
    srccol = 2048 + kvh * 128;
    dst = Ka + ((size_t)((b * 8 + kvh) * 2048 + s)) * 128;
    w = kw;
    scale = 1.0f;
  }
  const ushort* src = QKVp + ((size_t)(b * 2048 + s)) * 4096 + srccol;
  float x0 = bf2f(src[i]), x1 = bf2f(src[i + 64]);
  float ss = x0 * x0 + x1 * x1;
#pragma unroll
  for (int m = 1; m < 64; m <<= 1) ss += __shfl_xor(ss, m);
  float inv = rsqrtf(ss * (1.0f / 128.0f) + 1e-6f);
  float xn0 = x0 * inv * w[i], xn1 = x1 * inv * w[i + 64];
  const float* cp = cosb + ((size_t)(b * 2048 + s)) * 128;
  const float* sp = sinb + ((size_t)(b * 2048 + s)) * 128;
  float o0 = (xn0 * cp[i] - xn1 * sp[i]) * scale;
  float o1 = (xn1 * cp[i + 64] + xn0 * sp[i + 64]) * scale;
  dst[i] = (ushort)f2bfu(o0);
  dst[i + 64] = (ushort)f2bfu(o1);
}

// ---------------- V transpose -> Vt[b][kvh][d][s] ----------------
__global__ __launch_bounds__(256) void v_transpose(const ushort* __restrict__ QKVp,
                                                   ushort* __restrict__ Vt) {
  __shared__ ushort tile[64][136];
  int blk = blockIdx.x;
  int st = blk & 31, kvh = (blk >> 5) & 7, b = blk >> 8;
  int t = threadIdx.x;
  int s0 = st * 64;
  {
    int r = t >> 2, cseg = (t & 3) * 32;
    const ushort* src = QKVp + ((size_t)(b * 2048 + s0 + r)) * 4096 + 3072 + kvh * 128 + cseg;
#pragma unroll
    for (int i = 0; i < 4; ++i)
      *(uint4*)&tile[r][cseg + i * 8] = *(const uint4*)(src + i * 8);
  }
  __syncthreads();
  {
    int d = t >> 1, sh = (t & 1) * 32;
    ushort* dst = Vt + ((size_t)((b * 8 + kvh) * 128 + d)) * 2048 + s0 + sh;
    ushort buf[32];
#pragma unroll
    for (int k = 0; k < 32; ++k) buf[k] = tile[sh + k][d];
#pragma unroll
    for (int i = 0; i < 4; ++i) *(uint4*)(dst + i * 8) = *(uint4*)&buf[i * 8];
  }
}

// ---------------- Flash attention (unchanged from round 2) ----------------
__global__ __launch_bounds__(256, 2) void attn_kernel(const ushort* __restrict__ Qa,
                                                      const ushort* __restrict__ Ka,
                                                      const ushort* __restrict__ Vt,
                                                      ushort* __restrict__ Ctx) {
  __shared__ ushort Ks[64 * 128];
  __shared__ ushort Vs[128 * 64];
  __shared__ ushort Ps[8 * 1024];
  const int bh = blockIdx.x, b = bh >> 4, h = bh & 15, kvh = h >> 1;
  const int t = threadIdx.x, w = t >> 6, l = t & 63, lr = l & 15, lg = l >> 4;
  const int q0 = blockIdx.y * 128 + w * 32;
  const ushort* Qh = Qa + ((size_t)(b * 16 + h)) * 2048 * 128;
  const ushort* Kh = Ka + ((size_t)(b * 8 + kvh)) * 2048 * 128;
  const ushort* Vh = Vt + ((size_t)(b * 8 + kvh)) * 128 * 2048;

  short8 bq[2][4];
#pragma unroll
  for (int qt = 0; qt < 2; ++qt)
#pragma unroll
    for (int dc = 0; dc < 4; ++dc)
      bq[qt][dc] = *(const short8*)&Qh[(size_t)(q0 + qt * 16 + lr) * 128 + dc * 32 + lg * 8];

  f32x4 accO[8][2] = {};
  float mrun[2] = {-3.0e38f, -3.0e38f};
  float lrun[2] = {0.f, 0.f};

  for (int kt0 = 0; kt0 < 2048; kt0 += 64) {
    __syncthreads();
#pragma unroll
    for (int i = 0; i < 4; ++i) {
      const int c = w * 4 + i;
      const int krow = c * 4 + lg;
      gl_lds16(Kh + (size_t)(kt0 + krow) * 128 + (((l & 15) ^ (krow & 7)) * 8),
               &Ks[c * 512]);
      const int vrow = c * 8 + (l >> 3);
      gl_lds16(Vh + (size_t)vrow * 2048 + kt0 + (((l & 7) ^ ((l >> 3) & 7)) * 8),
               &Vs[c * 512]);
    }
    asm volatile("s_waitcnt vmcnt(0)" ::: "memory");
    __syncthreads();

    f32x4 accS[4][2] = {};
#pragma unroll
    for (int dc = 0; dc < 4; ++dc) {
      short8 ak[4];
#pragma unroll
      for (int kts = 0; kts < 4; ++kts)
        ak[kts] = *(const short8*)&Ks[(kts * 16 + lr) * 128 + ((dc * 4 + lg) ^ (lr & 7)) * 8];
#pragma unroll
      for (int kts = 0; kts < 4; ++kts)
#pragma unroll
        for (int qt = 0; qt < 2; ++qt)
          accS[kts][qt] = MFMA16(ak[kts], bq[qt][dc], accS[kts][qt]);
    }

#pragma unroll
    for (int qt = 0; qt < 2; ++qt) {
      float m0 = fmaxf(fmaxf(accS[0][qt][0], accS[0][qt][1]), fmaxf(accS[0][qt][2], accS[0][qt][3]));
      float m1 = fmaxf(fmaxf(accS[1][qt][0], accS[1][qt][1]), fmaxf(accS[1][qt][2], accS[1][qt][3]));
      float m2 = fmaxf(fmaxf(accS[2][qt][0], accS[2][qt][1]), fmaxf(accS[2][qt][2], accS[2][qt][3]));
      float m3 = fmaxf(fmaxf(accS[3][qt][0], accS[3][qt][1]), fmaxf(accS[3][qt][2], accS[3][qt][3]));
      float tm = fmaxf(fmaxf(m0, m1), fmaxf(m2, m3));
      tm = fmaxf(tm, __shfl_xor(tm, 16));
      tm = fmaxf(tm, __shfl_xor(tm, 32));
      if (!__all(tm <= mrun[qt] + 11.0f)) {
        float nm = fmaxf(mrun[qt], tm);
        float cf = exp2f(mrun[qt] - nm);
#pragma unroll
        for (int dc = 0; dc < 8; ++dc) {
          accO[dc][qt][0] *= cf; accO[dc][qt][1] *= cf;
          accO[dc][qt][2] *= cf; accO[dc][qt][3] *= cf;
        }
        lrun[qt] *= cf;
        mrun[qt] = nm;
      }
      float ts = 0.f;
#pragma unroll
      for (int kts = 0; kts < 4; ++kts)
#pragma unroll
        for (int j = 0; j < 4; ++j) {
          float p = exp2f(accS[kts][qt][j] - mrun[qt]);
          accS[kts][qt][j] = p;
          ts += p;
        }
      ts += __shfl_xor(ts, 16);
      ts += __shfl_xor(ts, 32);
      lrun[qt] += ts;
#pragma unroll
      for (int kts = 0; kts < 4; ++kts) {
        u32x2 pv;
        pv[0] = pk2(accS[kts][qt][0], accS[kts][qt][1]);
        pv[1] = pk2(accS[kts][qt][2], accS[kts][qt][3]);
        *(u32x2*)&Ps[(w * 2 + qt) * 1024 + lr * 64 +
                     (((kts * 2 + (lg >> 1)) ^ (lr & 7)) * 8 + (lg & 1) * 4)] = pv;
      }
    }
    asm volatile("s_waitcnt lgkmcnt(0)" ::: "memory");

    short8 bp[2][2];
#pragma unroll
    for (int qt = 0; qt < 2; ++qt)
#pragma unroll
      for (int ks = 0; ks < 2; ++ks)
        bp[qt][ks] = *(const short8*)&Ps[(w * 2 + qt) * 1024 + lr * 64 +
                                         ((ks * 4 + lg) ^ (lr & 7)) * 8];
#pragma unroll
    for (int dc = 0; dc < 8; ++dc) {
      short8 av[2];
#pragma unroll
      for (int ks = 0; ks < 2; ++ks)
        av[ks] = *(const short8*)&Vs[(dc * 16 + lr) * 64 + ((ks * 4 + lg) ^ (lr & 7)) * 8];
#pragma unroll
      for (int ks = 0; ks < 2; ++ks)
#pragma unroll
        for (int qt = 0; qt < 2; ++qt)
          accO[dc][qt] = MFMA16(av[ks], bp[qt][ks], accO[dc][qt]);
    }
  }

#pragma unroll
  for (int qt = 0; qt < 2; ++qt) {
    float inv = 1.0f / lrun[qt];
    int srow = q0 + qt * 16 + lr;
#pragma unroll
    for (int dc = 0; dc < 8; ++dc) {
      u32x2 ov;
      ov[0] = pk2(accO[dc][qt][0] * inv, accO[dc][qt][1] * inv);
      ov[1] = pk2(accO[dc][qt][2] * inv, accO[dc][qt][3] * inv);
      *(u32x2*)&Ctx[(size_t)(b * 2048 + srow) * 2048 + h * 128 + dc * 16 + lg * 4] = ov;
    }
  }
}

// ---------------- host ----------------
extern "C" void kernel_launch(void* const* d_in, const int* in_sizes, int n_in,
                              void* d_out, int out_size, void* d_ws, size_t ws_size,
                              hipStream_t stream) {
  const float* hidden = (const float*)d_in[0];
  const float* cosb   = (const float*)d_in[1];
  const float* sinb   = (const float*)d_in[2];
  const float* Wq     = (const float*)d_in[3];
  const float* Wk     = (const float*)d_in[4];
  const float* Wv     = (const float*)d_in[5];
  const float* Wo     = (const float*)d_in[6];
  const float* qw     = (const float*)d_in[7];
  const float* kw     = (const float*)d_in[8];

  char* ws = (char*)d_ws;
  ushort* Xb    = (ushort*)ws; ws += (size_t)4096 * 2048 * 2;
  ushort* Wcomb = (ushort*)ws; ws += (size_t)4096 * 2048 * 2;
  ushort* Wob   = (ushort*)ws; ws += (size_t)2048 * 2048 * 2;
  ushort* QKVp  = (ushort*)ws; ws += (size_t)4096 * 4096 * 2;
  ushort* Qa    = (ushort*)ws; ws += (size_t)2 * 16 * 2048 * 128 * 2;
  ushort* Ka    = (ushort*)ws; ws += (size_t)2 * 8 * 2048 * 128 * 2;
  ushort* Vt    = (ushort*)ws; ws += (size_t)2 * 8 * 2048 * 128 * 2;
  ushort* Ctx   = (ushort*)ws; ws += (size_t)4096 * 2048 * 2;

  f2b8<<<4096, 256, 0, stream>>>(hidden, Xb, 8388608);
  f2b8<<<2048, 256, 0, stream>>>(Wq, Wcomb, 4194304);
  f2b8<<<1024, 256, 0, stream>>>(Wk, Wcomb + 4194304, 2097152);
  f2b8<<<1024, 256, 0, stream>>>(Wv, Wcomb + 6291456, 2097152);
  f2b8<<<2048, 256, 0, stream>>>(Wo, Wob, 4194304);

  gemm256<0><<<dim3(16, 16), 512, 0, stream>>>(Xb, Wcomb, (void*)QKVp, 4096, 4096, 2048);

  qk_norm_rope<<<24576, 256, 0, stream>>>(QKVp, cosb, sinb, qw, kw, Qa, Ka);
  v_transpose<<<512, 256, 0, stream>>>(QKVp, Vt);

  attn_kernel<<<dim3(32, 16), 256, 0, stream>>>(Qa, Ka, Vt, Ctx);

  gemm256<1><<<dim3(16, 8), 512, 0, stream>>>(Ctx, Wob, d_out, 4096, 2048, 2048);
}

// Round 4
// 362.283 us; speedup vs baseline: 1.5222x; 1.0465x over previous
//
#include <hip/hip_runtime.h>

using short8 = __attribute__((ext_vector_type(8))) short;
using f32x4  = __attribute__((ext_vector_type(4))) float;
using u32x2  = __attribute__((ext_vector_type(2))) unsigned int;
using u32x4  = __attribute__((ext_vector_type(4))) unsigned int;

#define MFMA16(a, b, c) __builtin_amdgcn_mfma_f32_16x16x32_bf16((a), (b), (c), 0, 0, 0)

__device__ inline float bf2f(ushort v) { return __uint_as_float(((unsigned int)v) << 16); }
__device__ inline unsigned int f2bfu(float f) {
  unsigned int u = __float_as_uint(f);
  return (u + 0x7fffu + ((u >> 16) & 1u)) >> 16;   // RNE
}
__device__ inline unsigned int pk2(float a, float b) { return f2bfu(a) | (f2bfu(b) << 16); }

__device__ inline void gl_lds16(const ushort* g, ushort* l) {
  __builtin_amdgcn_global_load_lds(
      (const __attribute__((address_space(1))) void*)g,
      (__attribute__((address_space(3))) void*)l, 16, 0, 0);
}

// ---------------- fp32 -> bf16 convert, 8 elems/thread ----------------
__global__ __launch_bounds__(256) void f2b8(const float* __restrict__ src,
                                            ushort* __restrict__ dst, int n) {
  int i = (blockIdx.x * 256 + threadIdx.x) * 8;
  if (i >= n) return;
  f32x4 a = *(const f32x4*)(src + i);
  f32x4 b = *(const f32x4*)(src + i + 4);
  u32x4 o;
  o[0] = pk2(a[0], a[1]); o[1] = pk2(a[2], a[3]);
  o[2] = pk2(b[0], b[1]); o[3] = pk2(b[2], b[3]);
  *(u32x4*)(dst + i) = o;
}

// ---------------- 256x256 8-phase bf16 GEMM (unchanged from round 3) ----------------
#define GPHASE(CB, P, STG, VMW)                                                     \
  {                                                                                 \
    if (P == 0) {                                                                   \
      _Pragma("unroll") for (int n = 0; n < 4; ++n) {                               \
        bf[n][0] = *(const short8*)&L[(CB)*32768 + bBase + n*1024 + rdoff];         \
        bf[n][1] = *(const short8*)&L[(CB)*32768 + bBase + n*1024 + (rdoff ^ 32)];  \
      }                                                                             \
    }                                                                               \
    short8 af[2][2];                                                                \
    _Pragma("unroll") for (int mi = 0; mi < 2; ++mi) {                              \
      af[mi][0] = *(const short8*)&L[(CB)*32768 + aBase + ((P)*2+mi)*1024 + rdoff];        \
      af[mi][1] = *(const short8*)&L[(CB)*32768 + aBase + ((P)*2+mi)*1024 + (rdoff ^ 32)]; \
    }                                                                               \
    STG;                                                                            \
    __builtin_amdgcn_s_barrier();                                                   \
    asm volatile("s_waitcnt lgkmcnt(0)" ::: "memory");                              \
    __builtin_amdgcn_s_setprio(1);                                                  \
    _Pragma("unroll") for (int mi = 0; mi < 2; ++mi)                                \
      _Pragma("unroll") for (int n = 0; n < 4; ++n) {                               \
        acc[(P)*2+mi][n] = MFMA16(af[mi][0], bf[n][0], acc[(P)*2+mi][n]);           \
        acc[(P)*2+mi][n] = MFMA16(af[mi][1], bf[n][1], acc[(P)*2+mi][n]);           \
      }                                                                             \
    __builtin_amdgcn_s_setprio(0);                                                  \
    VMW;                                                                            \
    __builtin_amdgcn_s_barrier();                                                   \
  }

#define VM4 asm volatile("s_waitcnt vmcnt(4)" ::: "memory")
#define NOPX (void)0

template <int OUTF32>
__global__ __launch_bounds__(512, 2) void gemm256(const ushort* __restrict__ A,
                                                  const ushort* __restrict__ B,
                                                  void* __restrict__ Cv,
                                                  int M, int N, int K) {
  __shared__ ushort L[65536];  // 128 KiB
  const int t = threadIdx.x;
  const int w = t >> 6, l = t & 63, lr = l & 15, lg = l >> 4;
  const int wr = w >> 2, wc = w & 3;
  const int m0 = blockIdx.x * 256, n0 = blockIdx.y * 256;
  const int NT = K >> 6, NI = NT >> 1;

  f32x4 acc[8][4] = {};

  const int rdoff = lr * 64 + ((lg ^ (lr & 7)) * 8);
  const int aBase = wr * 8192;
  const int bBase = 16384 + (wc >> 1) * 8192 + (wc & 1) * 4096;

  const int ch0 = w * 2, ch1 = w * 2 + 1;
  const int srow0 = ch0 * 8 + (l >> 3), srow1 = ch1 * 8 + (l >> 3);
  const int scol = ((l & 7) ^ (l >> 3)) * 8;

  auto stage_a = [&](int h, int kt, int cb) {
    int ktc = kt < NT ? kt : NT - 1;
    gl_lds16(A + (size_t)(m0 + h * 128 + srow0) * K + ktc * 64 + scol,
             (ushort*)&L[cb * 32768 + h * 8192 + ch0 * 512]);
    gl_lds16(A + (size_t)(m0 + h * 128 + srow1) * K + ktc * 64 + scol,
             (ushort*)&L[cb * 32768 + h * 8192 + ch1 * 512]);
  };
  auto stage_b = [&](int h, int kt, int cb) {
    int ktc = kt < NT ? kt : NT - 1;
    gl_lds16(B + (size_t)(n0 + h * 128 + srow0) * K + ktc * 64 + scol,
             (ushort*)&L[cb * 32768 + 16384 + h * 8192 + ch0 * 512]);
    gl_lds16(B + (size_t)(n0 + h * 128 + srow1) * K + ktc * 64 + scol,
             (ushort*)&L[cb * 32768 + 16384 + h * 8192 + ch1 * 512]);
  };

  stage_a(0, 0, 0); stage_a(1, 0, 0); stage_b(0, 0, 0); stage_b(1, 0, 0);
  stage_b(0, 1, 1); stage_b(1, 1, 1);
  VM4;
  __builtin_amdgcn_s_barrier();

  short8 bf[4][2];
  for (int I = 0; I < NI; ++I) {
    const int t1 = 2 * I + 1, t2 = 2 * I + 2, t3 = 2 * I + 3;
    GPHASE(0, 0, stage_a(0, t1, 1), NOPX)
    GPHASE(0, 1, stage_a(1, t1, 1), NOPX)
    GPHASE(0, 2, stage_b(0, t2, 0), NOPX)
    GPHASE(0, 3, stage_b(1, t2, 0), VM4)
    GPHASE(1, 0, stage_a(0, t2, 0), NOPX)
    GPHASE(1, 1, stage_a(1, t2, 0), NOPX)
    GPHASE(1, 2, stage_b(0, t3, 1), NOPX)
    GPHASE(1, 3, stage_b(1, t3, 1), VM4)
  }

  const int crow0 = m0 + wr * 128 + lg * 4;
  const int ccol = n0 + wc * 64 + lr;
  if (OUTF32) {
    float* C = (float*)Cv;
#pragma unroll
    for (int m = 0; m < 8; ++m)
#pragma unroll
      for (int n = 0; n < 4; ++n)
#pragma unroll
        for (int j = 0; j < 4; ++j)
          C[(size_t)(crow0 + m * 16 + j) * N + ccol + n * 16] = acc[m][n][j];
  } else {
    ushort* C = (ushort*)Cv;
#pragma unroll
    for (int m = 0; m < 8; ++m)
#pragma unroll
      for (int n = 0; n < 4; ++n)
#pragma unroll
        for (int j = 0; j < 4; ++j)
          C[(size_t)(crow0 + m * 16 + j) * N + ccol + n * 16] = (ushort)f2bfu(acc[m][n][j]);
  }
}

// ---------------- RMSNorm + RoPE for Q and K ----------------
__global__ __launch_bounds__(256) void qk_norm_rope(
    const ushort* __restrict__ QKVp, const float* __restrict__ cosb,
    const float* __restrict__ sinb, const float* __restrict__ qw,
    const float* __restrict__ kw, ushort* __restrict__ Qa, ushort* __restrict__ Ka) {
  int r = blockIdx.x * 4 + (threadIdx.x >> 6);
  int i = threadIdx.x & 63;
  int b, s, srccol;
  ushort* dst;
  const float* w;
  float scale;
  if (r < 65536) {                       // Q rows
    b = r >> 15; int rem = r & 32767; s = rem >> 4; int h = rem & 15;
    srccol = h * 128;
    dst = Qa + ((size_t)((b * 16 + h) * 2048 + s)) * 128;
    w = qw;
    scale = 0.08838834764831845f * 1.4426950408889634f;  // HD^-0.5 * log2(e)
  } else {                               // K rows
    int rk = r - 65536;
    b = rk >> 14; int rem = rk & 16383; s = rem >> 3; int kvh = rem & 7;
    srccol = 2048 + kvh * 128;
    dst = Ka + ((size_t)((b * 8 + kvh) * 2048 + s)) * 128;
    w = kw;
    scale = 1.0f;
  }
  const ushort* src = QKVp + ((size_t)(b * 2048 + s)) * 4096 + srccol;
  float x0 = bf2f(src[i]), x1 = bf2f(src[i + 64]);
  float ss = x0 * x0 + x1 * x1;
#pragma unroll
  for (int m = 1; m < 64; m <<= 1) ss += __shfl_xor(ss, m);
  float inv = rsqrtf(ss * (1.0f / 128.0f) + 1e-6f);
  float xn0 = x0 * inv * w[i], xn1 = x1 * inv * w[i + 64];
  const float* cp = cosb + ((size_t)(b * 2048 + s)) * 128;
  const float* sp = sinb + ((size_t)(b * 2048 + s)) * 128;
  float o0 = (xn0 * cp[i] - xn1 * sp[i]) * scale;
  float o1 = (xn1 * cp[i + 64] + xn0 * sp[i + 64]) * scale;
  dst[i] = (ushort)f2bfu(o0);
  dst[i + 64] = (ushort)f2bfu(o1);
}

// ---------------- V transpose -> Vt[b][kvh][d][s] ----------------
__global__ __launch_bounds__(256) void v_transpose(const ushort* __restrict__ QKVp,
                                                   ushort* __restrict__ Vt) {
  __shared__ ushort tile[64][136];
  int blk = blockIdx.x;
  int st = blk & 31, kvh = (blk >> 5) & 7, b = blk >> 8;
  int t = threadIdx.x;
  int s0 = st * 64;
  {
    int r = t >> 2, cseg = (t & 3) * 32;
    const ushort* src = QKVp + ((size_t)(b * 2048 + s0 + r)) * 4096 + 3072 + kvh * 128 + cseg;
#pragma unroll
    for (int i = 0; i < 4; ++i)
      *(uint4*)&tile[r][cseg + i * 8] = *(const uint4*)(src + i * 8);
  }
  __syncthreads();
  {
    int d = t >> 1, sh = (t & 1) * 32;
    ushort* dst = Vt + ((size_t)((b * 8 + kvh) * 128 + d)) * 2048 + s0 + sh;
    ushort buf[32];
#pragma unroll
    for (int k = 0; k < 32; ++k) buf[k] = tile[sh + k][d];
#pragma unroll
    for (int i = 0; i < 4; ++i) *(uint4*)(dst + i * 8) = *(uint4*)&buf[i * 8];
  }
}

// ---------------- Flash attention v3: double-buffered K/V + counted vmcnt ----------------
// 4 waves x 32 q-rows. KVBLK=64. Stage tile t+2 into the buffer tile t vacated;
// vmcnt(8) waits only for tile t+1 (the 8 just-issued stay in flight).
__global__ __launch_bounds__(256, 2) void attn_kernel(const ushort* __restrict__ Qa,
                                                      const ushort* __restrict__ Ka,
                                                      const ushort* __restrict__ Vt,
                                                      ushort* __restrict__ Ctx) {
  __shared__ ushort Ks[2][64 * 128];   // 2 x 16KB, slot ^= (row&7) content
  __shared__ ushort Vs[2][128 * 64];   // 2 x 16KB
  __shared__ ushort Ps[8 * 1024];      // 16KB, per (wave,qt) private
  const int bh = blockIdx.x, b = bh >> 4, h = bh & 15, kvh = h >> 1;
  const int t = threadIdx.x, w = t >> 6, l = t & 63, lr = l & 15, lg = l >> 4;
  const int q0 = blockIdx.y * 128 + w * 32;
  const ushort* Qh = Qa + ((size_t)(b * 16 + h)) * 2048 * 128;
  const ushort* Kh = Ka + ((size_t)(b * 8 + kvh)) * 2048 * 128;
  const ushort* Vh = Vt + ((size_t)(b * 8 + kvh)) * 128 * 2048;

  // Q fragments first, then drain so vmcnt counting below is exact.
  short8 bq[2][4];
#pragma unroll
  for (int qt = 0; qt < 2; ++qt)
#pragma unroll
    for (int dc = 0; dc < 4; ++dc)
      bq[qt][dc] = *(const short8*)&Qh[(size_t)(q0 + qt * 16 + lr) * 128 + dc * 32 + lg * 8];
  asm volatile("s_waitcnt vmcnt(0)" ::: "memory");

  f32x4 accO[8][2] = {};
  float mrun[2] = {-3.0e38f, -3.0e38f};
  float lrun[2] = {0.f, 0.f};

  auto stage = [&](int kt0, ushort* KSB, ushort* VSB) {
#pragma unroll
    for (int i = 0; i < 4; ++i) {
      const int c = w * 4 + i;
      const int krow = c * 4 + lg;
      gl_lds16(Kh + (size_t)(kt0 + krow) * 128 + (((l & 15) ^ (krow & 7)) * 8),
               KSB + c * 512);
      const int vrow = c * 8 + (l >> 3);
      gl_lds16(Vh + (size_t)vrow * 2048 + kt0 + (((l & 7) ^ ((l >> 3) & 7)) * 8),
               VSB + c * 512);
    }
  };

  auto iter = [&](int kt, const ushort* KSB, const ushort* VSB, ushort* KSN, ushort* VSN) {
    // ---- QK^T (S^T: rows=k, cols=q) ----
    f32x4 accS[4][2] = {};
#pragma unroll
    for (int dc = 0; dc < 4; ++dc) {
      short8 ak[4];
#pragma unroll
      for (int kts = 0; kts < 4; ++kts)
        ak[kts] = *(const short8*)&KSB[(kts * 16 + lr) * 128 + ((dc * 4 + lg) ^ (lr & 7)) * 8];
#pragma unroll
      for (int kts = 0; kts < 4; ++kts)
#pragma unroll
        for (int qt = 0; qt < 2; ++qt)
          accS[kts][qt] = MFMA16(ak[kts], bq[qt][dc], accS[kts][qt]);
    }

    // ---- online softmax ----
#pragma unroll
    for (int qt = 0; qt < 2; ++qt) {
      float m0 = fmaxf(fmaxf(accS[0][qt][0], accS[0][qt][1]), fmaxf(accS[0][qt][2], accS[0][qt][3]));
      float m1 = fmaxf(fmaxf(accS[1][qt][0], accS[1][qt][1]), fmaxf(accS[1][qt][2], accS[1][qt][3]));
      float m2 = fmaxf(fmaxf(accS[2][qt][0], accS[2][qt][1]), fmaxf(accS[2][qt][2], accS[2][qt][3]));
      float m3 = fmaxf(fmaxf(accS[3][qt][0], accS[3][qt][1]), fmaxf(accS[3][qt][2], accS[3][qt][3]));
      float tm = fmaxf(fmaxf(m0, m1), fmaxf(m2, m3));
      tm = fmaxf(tm, __shfl_xor(tm, 16));
      tm = fmaxf(tm, __shfl_xor(tm, 32));
      if (!__all(tm <= mrun[qt] + 11.0f)) {        // T13 defer-rescale
        float nm = fmaxf(mrun[qt], tm);
        float cf = __builtin_amdgcn_exp2f(mrun[qt] - nm);
#pragma unroll
        for (int dc = 0; dc < 8; ++dc) {
          accO[dc][qt][0] *= cf; accO[dc][qt][1] *= cf;
          accO[dc][qt][2] *= cf; accO[dc][qt][3] *= cf;
        }
        lrun[qt] *= cf;
        mrun[qt] = nm;
      }
      float ts = 0.f;
#pragma unroll
      for (int kts = 0; kts < 4; ++kts)
#pragma unroll
        for (int j = 0; j < 4; ++j) {
          float p = __builtin_amdgcn_exp2f(accS[kts][qt][j] - mrun[qt]);
          accS[kts][qt][j] = p;
          ts += p;
        }
      ts += __shfl_xor(ts, 16);
      ts += __shfl_xor(ts, 32);
      lrun[qt] += ts;
#pragma unroll
      for (int kts = 0; kts < 4; ++kts) {
        u32x2 pv;
        pv[0] = pk2(accS[kts][qt][0], accS[kts][qt][1]);
        pv[1] = pk2(accS[kts][qt][2], accS[kts][qt][3]);
        *(u32x2*)&Ps[(w * 2 + qt) * 1024 + lr * 64 +
                     (((kts * 2 + (lg >> 1)) ^ (lr & 7)) * 8 + (lg & 1) * 4)] = pv;
      }
    }
    asm volatile("s_waitcnt lgkmcnt(0)" ::: "memory");

    // ---- PV ----
    short8 bp[2][2];
#pragma unroll
    for (int qt = 0; qt < 2; ++qt)
#pragma unroll
      for (int ks = 0; ks < 2; ++ks)
        bp[qt][ks] = *(const short8*)&Ps[(w * 2 + qt) * 1024 + lr * 64 +
                                         ((ks * 4 + lg) ^ (lr & 7)) * 8];
#pragma unroll
    for (int dc = 0; dc < 8; ++dc) {
      short8 av[2];
#pragma unroll
      for (int ks = 0; ks < 2; ++ks)
        av[ks] = *(const short8*)&VSB[(dc * 16 + lr) * 64 + ((ks * 4 + lg) ^ (lr & 7)) * 8];
#pragma unroll
      for (int ks = 0; ks < 2; ++ks)
#pragma unroll
        for (int qt = 0; qt < 2; ++qt)
          accO[dc][qt] = MFMA16(av[ks], bp[qt][ks], accO[dc][qt]);
    }

    // ---- pipeline control: free this buffer, refill it, wait next tile ----
    asm volatile("" ::: "memory");
    __builtin_amdgcn_s_barrier();                  // all waves done reading KSB/VSB
    if (kt + 128 <= 2048) {
      stage(kt + 128, KSN, VSN);
      asm volatile("s_waitcnt vmcnt(8)" ::: "memory");   // tile kt+64 landed
    } else {
      asm volatile("s_waitcnt vmcnt(0)" ::: "memory");
    }
    __builtin_amdgcn_s_barrier();                  // everyone's waits done
  };

  // prologue: tiles 0,1 in flight; wait tile 0.
  stage(0, Ks[0], Vs[0]);
  stage(64, Ks[1], Vs[1]);
  asm volatile("s_waitcnt vmcnt(8)" ::: "memory");
  __builtin_amdgcn_s_barrier();

  for (int t2 = 0; t2 < 2048; t2 += 128) {
    iter(t2,      Ks[0], Vs[0], Ks[0], Vs[0]);
    iter(t2 + 64, Ks[1], Vs[1], Ks[1], Vs[1]);
  }

#pragma unroll
  for (int qt = 0; qt < 2; ++qt) {
    float inv = 1.0f / lrun[qt];
    int srow = q0 + qt * 16 + lr;
#pragma unroll
    for (int dc = 0; dc < 8; ++dc) {
      u32x2 ov;
      ov[0] = pk2(accO[dc][qt][0] * inv, accO[dc][qt][1] * inv);
      ov[1] = pk2(accO[dc][qt][2] * inv, accO[dc][qt][3] * inv);
      *(u32x2*)&Ctx[(size_t)(b * 2048 + srow) * 2048 + h * 128 + dc * 16 + lg * 4] = ov;
    }
  }
}

// ---------------- host ----------------
extern "C" void kernel_launch(void* const* d_in, const int* in_sizes, int n_in,
                              void* d_out, int out_size, void* d_ws, size_t ws_size,
                              hipStream_t stream) {
  const float* hidden = (const float*)d_in[0];
  const float* cosb   = (const float*)d_in[1];
  const float* sinb   = (const float*)d_in[2];
  const float* Wq     = (const float*)d_in[3];
  const float* Wk     = (const float*)d_in[4];
  const float* Wv     = (const float*)d_in[5];
  const float* Wo     = (const float*)d_in[6];
  const float* qw     = (const float*)d_in[7];
  const float* kw     = (const float*)d_in[8];

  char* ws = (char*)d_ws;
  ushort* Xb    = (ushort*)ws; ws += (size_t)4096 * 2048 * 2;
  ushort* Wcomb = (ushort*)ws; ws += (size_t)4096 * 2048 * 2;
  ushort* Wob   = (ushort*)ws; ws += (size_t)2048 * 2048 * 2;
  ushort* QKVp  = (ushort*)ws; ws += (size_t)4096 * 4096 * 2;
  ushort* Qa    = (ushort*)ws; ws += (size_t)2 * 16 * 2048 * 128 * 2;
  ushort* Ka    = (ushort*)ws; ws += (size_t)2 * 8 * 2048 * 128 * 2;
  ushort* Vt    = (ushort*)ws; ws += (size_t)2 * 8 * 2048 * 128 * 2;
  ushort* Ctx   = (ushort*)ws; ws += (size_t)4096 * 2048 * 2;

  f2b8<<<4096, 256, 0, stream>>>(hidden, Xb, 8388608);
  f2b8<<<2048, 256, 0, stream>>>(Wq, Wcomb, 4194304);
  f2b8<<<1024, 256, 0, stream>>>(Wk, Wcomb + 4194304, 2097152);
  f2b8<<<1024, 256, 0, stream>>>(Wv, Wcomb + 6291456, 2097152);
  f2b8<<<2048, 256, 0, stream>>>(Wo, Wob, 4194304);

  gemm256<0><<<dim3(16, 16), 512, 0, stream>>>(Xb, Wcomb, (void*)QKVp, 4096, 4096, 2048);

  qk_norm_rope<<<24576, 256, 0, stream>>>(QKVp, cosb, sinb, qw, kw, Qa, Ka);
  v_transpose<<<512, 256, 0, stream>>>(QKVp, Vt);

  attn_kernel<<<dim3(32, 16), 256, 0, stream>>>(Qa, Ka, Vt, Ctx);

  gemm256<1><<<dim3(16, 8), 512, 0, stream>>>(Ctx, Wob, d_out, 4096, 2048, 2048);
}

// Round 5
// 358.822 us; speedup vs baseline: 1.5368x; 1.0096x over previous
//
#include <hip/hip_runtime.h>

using short8 = __attribute__((ext_vector_type(8))) short;
using f32x4  = __attribute__((ext_vector_type(4))) float;
using u32x2  = __attribute__((ext_vector_type(2))) unsigned int;
using u32x4  = __attribute__((ext_vector_type(4))) unsigned int;

#define MFMA16(a, b, c) __builtin_amdgcn_mfma_f32_16x16x32_bf16((a), (b), (c), 0, 0, 0)

__device__ inline float bf2f(ushort v) { return __uint_as_float(((unsigned int)v) << 16); }
__device__ inline unsigned int f2bfu(float f) {
  unsigned int u = __float_as_uint(f);
  return (u + 0x7fffu + ((u >> 16) & 1u)) >> 16;   // RNE
}
__device__ inline unsigned int pk2(float a, float b) { return f2bfu(a) | (f2bfu(b) << 16); }
__device__ inline unsigned int pk2hw(float lo, float hi) {
  unsigned int r;
  asm("v_cvt_pk_bf16_f32 %0, %1, %2" : "=v"(r) : "v"(lo), "v"(hi));
  return r;
}

__device__ inline void gl_lds16(const ushort* g, ushort* l) {
  __builtin_amdgcn_global_load_lds(
      (const __attribute__((address_space(1))) void*)g,
      (__attribute__((address_space(3))) void*)l, 16, 0, 0);
}

// ---------------- fp32 -> bf16 convert (hidden states) ----------------
__global__ __launch_bounds__(256) void f2b8(const float* __restrict__ src,
                                            ushort* __restrict__ dst, int n) {
  int i = (blockIdx.x * 256 + threadIdx.x) * 8;
  if (i >= n) return;
  f32x4 a = *(const f32x4*)(src + i);
  f32x4 b = *(const f32x4*)(src + i + 4);
  u32x4 o;
  o[0] = pk2(a[0], a[1]); o[1] = pk2(a[2], a[3]);
  o[2] = pk2(b[0], b[1]); o[3] = pk2(b[2], b[3]);
  *(u32x4*)(dst + i) = o;
}

// ---------------- merged weight converts: Wq,Wk,Wv -> Wcomb; Wo -> Wob ----------------
__global__ __launch_bounds__(256) void wconv(const float* __restrict__ Wq,
                                             const float* __restrict__ Wk,
                                             const float* __restrict__ Wv,
                                             const float* __restrict__ Wo,
                                             ushort* __restrict__ Wcomb,
                                             ushort* __restrict__ Wob) {
  int blk = blockIdx.x;
  const float* src; ushort* dst; int off;
  if (blk < 2048)      { src = Wq; dst = Wcomb;           off = blk * 2048; }
  else if (blk < 3072) { src = Wk; dst = Wcomb + 4194304; off = (blk - 2048) * 2048; }
  else if (blk < 4096) { src = Wv; dst = Wcomb + 6291456; off = (blk - 3072) * 2048; }
  else                 { src = Wo; dst = Wob;             off = (blk - 4096) * 2048; }
  int i = off + threadIdx.x * 8;
  f32x4 a = *(const f32x4*)(src + i);
  f32x4 b = *(const f32x4*)(src + i + 4);
  u32x4 o;
  o[0] = pk2(a[0], a[1]); o[1] = pk2(a[2], a[3]);
  o[2] = pk2(b[0], b[1]); o[3] = pk2(b[2], b[3]);
  *(u32x4*)(dst + i) = o;
}

// ---------------- 256x256 8-phase bf16 GEMM (unchanged, QKV only) ----------------
#define GPHASE(CB, P, STG, VMW)                                                     \
  {                                                                                 \
    if (P == 0) {                                                                   \
      _Pragma("unroll") for (int n = 0; n < 4; ++n) {                               \
        bf[n][0] = *(const short8*)&L[(CB)*32768 + bBase + n*1024 + rdoff];         \
        bf[n][1] = *(const short8*)&L[(CB)*32768 + bBase + n*1024 + (rdoff ^ 32)];  \
      }                                                                             \
    }                                                                               \
    short8 af[2][2];                                                                \
    _Pragma("unroll") for (int mi = 0; mi < 2; ++mi) {                              \
      af[mi][0] = *(const short8*)&L[(CB)*32768 + aBase + ((P)*2+mi)*1024 + rdoff];        \
      af[mi][1] = *(const short8*)&L[(CB)*32768 + aBase + ((P)*2+mi)*1024 + (rdoff ^ 32)]; \
    }                                                                               \
    STG;                                                                            \
    __builtin_amdgcn_s_barrier();                                                   \
    asm volatile("s_waitcnt lgkmcnt(0)" ::: "memory");                              \
    __builtin_amdgcn_s_setprio(1);                                                  \
    _Pragma("unroll") for (int mi = 0; mi < 2; ++mi)                                \
      _Pragma("unroll") for (int n = 0; n < 4; ++n) {                               \
        acc[(P)*2+mi][n] = MFMA16(af[mi][0], bf[n][0], acc[(P)*2+mi][n]);           \
        acc[(P)*2+mi][n] = MFMA16(af[mi][1], bf[n][1], acc[(P)*2+mi][n]);           \
      }                                                                             \
    __builtin_amdgcn_s_setprio(0);                                                  \
    VMW;                                                                            \
    __builtin_amdgcn_s_barrier();                                                   \
  }

#define VM4 asm volatile("s_waitcnt vmcnt(4)" ::: "memory")
#define NOPX (void)0

template <int OUTF32>
__global__ __launch_bounds__(512, 2) void gemm256(const ushort* __restrict__ A,
                                                  const ushort* __restrict__ B,
                                                  void* __restrict__ Cv,
                                                  int M, int N, int K) {
  __shared__ ushort L[65536];
  const int t = threadIdx.x;
  const int w = t >> 6, l = t & 63, lr = l & 15, lg = l >> 4;
  const int wr = w >> 2, wc = w & 3;
  const int m0 = blockIdx.x * 256, n0 = blockIdx.y * 256;
  const int NT = K >> 6, NI = NT >> 1;

  f32x4 acc[8][4] = {};

  const int rdoff = lr * 64 + ((lg ^ (lr & 7)) * 8);
  const int aBase = wr * 8192;
  const int bBase = 16384 + (wc >> 1) * 8192 + (wc & 1) * 4096;

  const int ch0 = w * 2, ch1 = w * 2 + 1;
  const int srow0 = ch0 * 8 + (l >> 3), srow1 = ch1 * 8 + (l >> 3);
  const int scol = ((l & 7) ^ (l >> 3)) * 8;

  auto stage_a = [&](int h, int kt, int cb) {
    int ktc = kt < NT ? kt : NT - 1;
    gl_lds16(A + (size_t)(m0 + h * 128 + srow0) * K + ktc * 64 + scol,
             (ushort*)&L[cb * 32768 + h * 8192 + ch0 * 512]);
    gl_lds16(A + (size_t)(m0 + h * 128 + srow1) * K + ktc * 64 + scol,
             (ushort*)&L[cb * 32768 + h * 8192 + ch1 * 512]);
  };
  auto stage_b = [&](int h, int kt, int cb) {
    int ktc = kt < NT ? kt : NT - 1;
    gl_lds16(B + (size_t)(n0 + h * 128 + srow0) * K + ktc * 64 + scol,
             (ushort*)&L[cb * 32768 + 16384 + h * 8192 + ch0 * 512]);
    gl_lds16(B + (size_t)(n0 + h * 128 + srow1) * K + ktc * 64 + scol,
             (ushort*)&L[cb * 32768 + 16384 + h * 8192 + ch1 * 512]);
  };

  stage_a(0, 0, 0); stage_a(1, 0, 0); stage_b(0, 0, 0); stage_b(1, 0, 0);
  stage_b(0, 1, 1); stage_b(1, 1, 1);
  VM4;
  __builtin_amdgcn_s_barrier();

  short8 bf[4][2];
  for (int I = 0; I < NI; ++I) {
    const int t1 = 2 * I + 1, t2 = 2 * I + 2, t3 = 2 * I + 3;
    GPHASE(0, 0, stage_a(0, t1, 1), NOPX)
    GPHASE(0, 1, stage_a(1, t1, 1), NOPX)
    GPHASE(0, 2, stage_b(0, t2, 0), NOPX)
    GPHASE(0, 3, stage_b(1, t2, 0), VM4)
    GPHASE(1, 0, stage_a(0, t2, 0), NOPX)
    GPHASE(1, 1, stage_a(1, t2, 0), NOPX)
    GPHASE(1, 2, stage_b(0, t3, 1), NOPX)
    GPHASE(1, 3, stage_b(1, t3, 1), VM4)
  }

  const int crow0 = m0 + wr * 128 + lg * 4;
  const int ccol = n0 + wc * 64 + lr;
  if (OUTF32) {
    float* C = (float*)Cv;
#pragma unroll
    for (int m = 0; m < 8; ++m)
#pragma unroll
      for (int n = 0; n < 4; ++n)
#pragma unroll
        for (int j = 0; j < 4; ++j)
          C[(size_t)(crow0 + m * 16 + j) * N + ccol + n * 16] = acc[m][n][j];
  } else {
    ushort* C = (ushort*)Cv;
#pragma unroll
    for (int m = 0; m < 8; ++m)
#pragma unroll
      for (int n = 0; n < 4; ++n)
#pragma unroll
        for (int j = 0; j < 4; ++j)
          C[(size_t)(crow0 + m * 16 + j) * N + ccol + n * 16] = (ushort)f2bfu(acc[m][n][j]);
  }
}

// ---------------- 128x256 8-phase bf16 GEMM, f32 out (Wo projection) ----------------
// 8 waves 2Mx4N, wave tile 64x64, acc[4][4]. Same swizzle + counted-vmcnt structure.
// Per-wave ops/stage: A-half=1, B-half=2. VM4 at ph3/ph7 (oldest 6 = prev tile's A+B).
#define GP128(CB, P, STG, VMW)                                                      \
  {                                                                                 \
    if (P == 0) {                                                                   \
      _Pragma("unroll") for (int n = 0; n < 4; ++n) {                               \
        bf[n][0] = *(const short8*)&L[(CB)*24576 + bBase + n*1024 + rdoff];         \
        bf[n][1] = *(const short8*)&L[(CB)*24576 + bBase + n*1024 + (rdoff ^ 32)];  \
      }                                                                             \
    }                                                                               \
    short8 af0 = *(const short8*)&L[(CB)*24576 + aBase + (P)*1024 + rdoff];         \
    short8 af1 = *(const short8*)&L[(CB)*24576 + aBase + (P)*1024 + (rdoff ^ 32)];  \
    STG;                                                                            \
    __builtin_amdgcn_s_barrier();                                                   \
    asm volatile("s_waitcnt lgkmcnt(0)" ::: "memory");                              \
    __builtin_amdgcn_s_setprio(1);                                                  \
    _Pragma("unroll") for (int n = 0; n < 4; ++n) {                                 \
      acc[(P)][n] = MFMA16(af0, bf[n][0], acc[(P)][n]);                             \
      acc[(P)][n] = MFMA16(af1, bf[n][1], acc[(P)][n]);                             \
    }                                                                               \
    __builtin_amdgcn_s_setprio(0);                                                  \
    VMW;                                                                            \
    __builtin_amdgcn_s_barrier();                                                   \
  }

__global__ __launch_bounds__(512, 2) void gemm128(const ushort* __restrict__ A,
                                                  const ushort* __restrict__ B,
                                                  float* __restrict__ C,
                                                  int M, int N, int K) {
  __shared__ ushort L[49152];  // 96 KiB: per buf 24576 (A 8192 + B 16384)
  const int t = threadIdx.x;
  const int w = t >> 6, l = t & 63, lr = l & 15, lg = l >> 4;
  const int wr = w >> 2, wc = w & 3;
  const int m0 = blockIdx.x * 128, n0 = blockIdx.y * 256;
  const int NT = K >> 6, NI = NT >> 1;

  f32x4 acc[4][4] = {};

  const int rdoff = lr * 64 + ((lg ^ (lr & 7)) * 8);
  const int aBase = wr * 4096;
  const int bBase = 8192 + wc * 4096;
  const int scol = ((l & 7) ^ (l >> 3)) * 8;

  auto stage_a_h = [&](int h, int kt, int cb) {      // chunk h*8 + w (8 rows)
    int ktc = kt < NT ? kt : NT - 1;
    int ch = h * 8 + w;
    gl_lds16(A + (size_t)(m0 + ch * 8 + (l >> 3)) * K + ktc * 64 + scol,
             (ushort*)&L[cb * 24576 + ch * 512]);
  };
  auto stage_b_h = [&](int h, int kt, int cb) {      // chunks h*16 + w*2, +1
    int ktc = kt < NT ? kt : NT - 1;
    int c0 = h * 16 + w * 2, c1 = c0 + 1;
    gl_lds16(B + (size_t)(n0 + c0 * 8 + (l >> 3)) * K + ktc * 64 + scol,
             (ushort*)&L[cb * 24576 + 8192 + c0 * 512]);
    gl_lds16(B + (size_t)(n0 + c1 * 8 + (l >> 3)) * K + ktc * 64 + scol,
             (ushort*)&L[cb * 24576 + 8192 + c1 * 512]);
  };

  // prologue: tile0 (A+B) -> buf0, tile1 B -> buf1; wait tile0 (6 ops), 4 allowed out
  stage_a_h(0, 0, 0); stage_a_h(1, 0, 0);
  stage_b_h(0, 0, 0); stage_b_h(1, 0, 0);
  stage_b_h(0, 1, 1); stage_b_h(1, 1, 1);
  VM4;
  __builtin_amdgcn_s_barrier();

  short8 bf[4][2];
  for (int I = 0; I < NI; ++I) {
    const int t1 = 2 * I + 1, t2 = 2 * I + 2, t3 = 2 * I + 3;
    GP128(0, 0, stage_a_h(0, t1, 1), NOPX)
    GP128(0, 1, stage_a_h(1, t1, 1), NOPX)
    GP128(0, 2, stage_b_h(0, t2, 0), NOPX)
    GP128(0, 3, stage_b_h(1, t2, 0), VM4)
    GP128(1, 0, stage_a_h(0, t2, 0), NOPX)
    GP128(1, 1, stage_a_h(1, t2, 0), NOPX)
    GP128(1, 2, stage_b_h(0, t3, 1), NOPX)
    GP128(1, 3, stage_b_h(1, t3, 1), VM4)
  }

  const int crow0 = m0 + wr * 64 + lg * 4;
  const int ccol = n0 + wc * 64 + lr;
#pragma unroll
  for (int m = 0; m < 4; ++m)
#pragma unroll
    for (int n = 0; n < 4; ++n)
#pragma unroll
      for (int j = 0; j < 4; ++j)
        C[(size_t)(crow0 + m * 16 + j) * N + ccol + n * 16] = acc[m][n][j];
}

// ---------------- RMSNorm + RoPE for Q and K ----------------
__global__ __launch_bounds__(256) void qk_norm_rope(
    const ushort* __restrict__ QKVp, const float* __restrict__ cosb,
    const float* __restrict__ sinb, const float* __restrict__ qw,
    const float* __restrict__ kw, ushort* __restrict__ Qa, ushort* __restrict__ Ka) {
  int r = blockIdx.x * 4 + (threadIdx.x >> 6);
  int i = threadIdx.x & 63;
  int b, s, srccol;
  ushort* dst;
  const float* w;
  float scale;
  if (r < 65536) {                       // Q rows
    b = r >> 15; int rem = r & 32767; s = rem >> 4; int h = rem & 15;
    srccol = h * 128;
    dst = Qa + ((size_t)((b * 16 + h) * 2048 + s)) * 128;
    w = qw;
    scale = 0.08838834764831845f * 1.4426950408889634f;  // HD^-0.5 * log2(e)
  } else {                               // K rows
    int rk = r - 65536;
    b = rk >> 14; int rem = rk & 16383; s = rem >> 3; int kvh = rem & 7;
    srccol = 2048 + kvh * 128;
    dst = Ka + ((size_t)((b * 8 + kvh) * 2048 + s)) * 128;
    w = kw;
    scale = 1.0f;
  }
  const ushort* src = QKVp + ((size_t)(b * 2048 + s)) * 4096 + srccol;
  float x0 = bf2f(src[i]), x1 = bf2f(src[i + 64]);
  float ss = x0 * x0 + x1 * x1;
#pragma unroll
  for (int m = 1; m < 64; m <<= 1) ss += __shfl_xor(ss, m);
  float inv = rsqrtf(ss * (1.0f / 128.0f) + 1e-6f);
  float xn0 = x0 * inv * w[i], xn1 = x1 * inv * w[i + 64];
  const float* cp = cosb + ((size_t)(b * 2048 + s)) * 128;
  const float* sp = sinb + ((size_t)(b * 2048 + s)) * 128;
  float o0 = (xn0 * cp[i] - xn1 * sp[i]) * scale;
  float o1 = (xn1 * cp[i + 64] + xn0 * sp[i + 64]) * scale;
  dst[i] = (ushort)f2bfu(o0);
  dst[i + 64] = (ushort)f2bfu(o1);
}

// ---------------- V transpose -> Vt[b][kvh][d][s] ----------------
__global__ __launch_bounds__(256) void v_transpose(const ushort* __restrict__ QKVp,
                                                   ushort* __restrict__ Vt) {
  __shared__ ushort tile[64][136];
  int blk = blockIdx.x;
  int st = blk & 31, kvh = (blk >> 5) & 7, b = blk >> 8;
  int t = threadIdx.x;
  int s0 = st * 64;
  {
    int r = t >> 2, cseg = (t & 3) * 32;
    const ushort* src = QKVp + ((size_t)(b * 2048 + s0 + r)) * 4096 + 3072 + kvh * 128 + cseg;
#pragma unroll
    for (int i = 0; i < 4; ++i)
      *(uint4*)&tile[r][cseg + i * 8] = *(const uint4*)(src + i * 8);
  }
  __syncthreads();
  {
    int d = t >> 1, sh = (t & 1) * 32;
    ushort* dst = Vt + ((size_t)((b * 8 + kvh) * 128 + d)) * 2048 + s0 + sh;
    ushort buf[32];
#pragma unroll
    for (int k = 0; k < 32; ++k) buf[k] = tile[sh + k][d];
#pragma unroll
    for (int i = 0; i < 4; ++i) *(uint4*)(dst + i * 8) = *(uint4*)&buf[i * 8];
  }
}

// ---------------- Flash attention v4: 8 waves x 16 q-rows, dbuf K/V, cvt_pk ----------------
// 512 thr, 128 q/block, KVBLK=64. LDS 80KB -> 2 blocks/CU -> 16 waves/CU (50% cap).
// Per-wave stage = 4 gl_lds; counted vmcnt(4) keeps next tile in flight.
__global__ __launch_bounds__(512, 4) void attn_kernel(const ushort* __restrict__ Qa,
                                                      const ushort* __restrict__ Ka,
                                                      const ushort* __restrict__ Vt,
                                                      ushort* __restrict__ Ctx) {
  __shared__ ushort Ks[2][64 * 128];   // swizzled content: slot ^= (row&7)
  __shared__ ushort Vs[2][128 * 64];
  __shared__ ushort Ps[8 * 1024];      // per-wave [16 q][64 k], slot ^= (q&7)
  const int bh = blockIdx.x, b = bh >> 4, h = bh & 15, kvh = h >> 1;
  const int t = threadIdx.x, w = t >> 6, l = t & 63, lr = l & 15, lg = l >> 4;
  const int q0 = blockIdx.y * 128 + w * 16;
  const ushort* Qh = Qa + ((size_t)(b * 16 + h)) * 2048 * 128;
  const ushort* Kh = Ka + ((size_t)(b * 8 + kvh)) * 2048 * 128;
  const ushort* Vh = Vt + ((size_t)(b * 8 + kvh)) * 128 * 2048;

  short8 bq[4];
#pragma unroll
  for (int dc = 0; dc < 4; ++dc)
    bq[dc] = *(const short8*)&Qh[(size_t)(q0 + lr) * 128 + dc * 32 + lg * 8];
  asm volatile("s_waitcnt vmcnt(0)" ::: "memory");   // drain so vmcnt counting is exact

  f32x4 accO[8] = {};
  float mrun = -3.0e38f, lrun = 0.f;

  auto stage = [&](int kt0, ushort* KSB, ushort* VSB) {
#pragma unroll
    for (int i = 0; i < 2; ++i) {
      const int c = w * 2 + i;
      const int krow = c * 4 + lg;
      gl_lds16(Kh + (size_t)(kt0 + krow) * 128 + ((lr ^ (krow & 7)) * 8), KSB + c * 512);
      const int vrow = c * 8 + (l >> 3);
      gl_lds16(Vh + (size_t)vrow * 2048 + kt0 + (((l & 7) ^ ((l >> 3) & 7)) * 8), VSB + c * 512);
    }
  };

  auto iter = [&](int kt, ushort* KSB, ushort* VSB) {
    // ---- QK^T (S^T: rows=k, cols=q=lr) ----
    f32x4 accS[4] = {};
    __builtin_amdgcn_s_setprio(1);
#pragma unroll
    for (int dc = 0; dc < 4; ++dc) {
      short8 ak[4];
#pragma unroll
      for (int kts = 0; kts < 4; ++kts)
        ak[kts] = *(const short8*)&KSB[(kts * 16 + lr) * 128 + ((dc * 4 + lg) ^ (lr & 7)) * 8];
#pragma unroll
      for (int kts = 0; kts < 4; ++kts)
        accS[kts] = MFMA16(ak[kts], bq[dc], accS[kts]);
    }
    __builtin_amdgcn_s_setprio(0);

    // ---- online softmax (one q-tile), reduce over lg via shfl ----
    {
      float m0 = fmaxf(fmaxf(accS[0][0], accS[0][1]), fmaxf(accS[0][2], accS[0][3]));
      float m1 = fmaxf(fmaxf(accS[1][0], accS[1][1]), fmaxf(accS[1][2], accS[1][3]));
      float m2 = fmaxf(fmaxf(accS[2][0], accS[2][1]), fmaxf(accS[2][2], accS[2][3]));
      float m3 = fmaxf(fmaxf(accS[3][0], accS[3][1]), fmaxf(accS[3][2], accS[3][3]));
      float tm = fmaxf(fmaxf(m0, m1), fmaxf(m2, m3));
      tm = fmaxf(tm, __shfl_xor(tm, 16));
      tm = fmaxf(tm, __shfl_xor(tm, 32));
      if (!__all(tm <= mrun + 11.0f)) {            // T13 defer-rescale
        float nm = fmaxf(mrun, tm);
        float cf = __builtin_amdgcn_exp2f(mrun - nm);
#pragma unroll
        for (int dc = 0; dc < 8; ++dc) {
          accO[dc][0] *= cf; accO[dc][1] *= cf;
          accO[dc][2] *= cf; accO[dc][3] *= cf;
        }
        lrun *= cf;
        mrun = nm;
      }
      float ts = 0.f;
#pragma unroll
      for (int kts = 0; kts < 4; ++kts)
#pragma unroll
        for (int j = 0; j < 4; ++j) {
          float p = __builtin_amdgcn_exp2f(accS[kts][j] - mrun);
          accS[kts][j] = p;
          ts += p;
        }
      ts += __shfl_xor(ts, 16);
      ts += __shfl_xor(ts, 32);
      lrun += ts;
#pragma unroll
      for (int kts = 0; kts < 4; ++kts) {
        u32x2 pv;
        pv[0] = pk2hw(accS[kts][0], accS[kts][1]);
        pv[1] = pk2hw(accS[kts][2], accS[kts][3]);
        *(u32x2*)&Ps[w * 1024 + lr * 64 +
                     (((kts * 2 + (lg >> 1)) ^ (lr & 7)) * 8 + (lg & 1) * 4)] = pv;
      }
    }
    asm volatile("s_waitcnt lgkmcnt(0)" ::: "memory");

    // ---- PV ----
    short8 bp[2];
#pragma unroll
    for (int ks = 0; ks < 2; ++ks)
      bp[ks] = *(const short8*)&Ps[w * 1024 + lr * 64 + ((ks * 4 + lg) ^ (lr & 7)) * 8];
    __builtin_amdgcn_s_setprio(1);
#pragma unroll
    for (int dc = 0; dc < 8; ++dc) {
      short8 av[2];
#pragma unroll
      for (int ks = 0; ks < 2; ++ks)
        av[ks] = *(const short8*)&VSB[(dc * 16 + lr) * 64 + ((ks * 4 + lg) ^ (lr & 7)) * 8];
#pragma unroll
      for (int ks = 0; ks < 2; ++ks)
        accO[dc] = MFMA16(av[ks], bp[ks], accO[dc]);
    }
    __builtin_amdgcn_s_setprio(0);

    // ---- pipeline: free buffer, refill with tile kt+128, wait tile kt+64 ----
    asm volatile("" ::: "memory");
    __builtin_amdgcn_s_barrier();
    if (kt + 128 < 2048) {
      stage(kt + 128, KSB, VSB);
      asm volatile("s_waitcnt vmcnt(4)" ::: "memory");
    } else {
      asm volatile("s_waitcnt vmcnt(0)" ::: "memory");
    }
    __builtin_amdgcn_s_barrier();
  };

  stage(0, Ks[0], Vs[0]);
  stage(64, Ks[1], Vs[1]);
  asm volatile("s_waitcnt vmcnt(4)" ::: "memory");
  __builtin_amdgcn_s_barrier();

  for (int t2 = 0; t2 < 2048; t2 += 128) {
    iter(t2,      Ks[0], Vs[0]);
    iter(t2 + 64, Ks[1], Vs[1]);
  }

  {
    float inv = 1.0f / lrun;
    int srow = q0 + lr;
#pragma unroll
    for (int dc = 0; dc < 8; ++dc) {
      u32x2 ov;
      ov[0] = pk2hw(accO[dc][0] * inv, accO[dc][1] * inv);
      ov[1] = pk2hw(accO[dc][2] * inv, accO[dc][3] * inv);
      *(u32x2*)&Ctx[(size_t)(b * 2048 + srow) * 2048 + h * 128 + dc * 16 + lg * 4] = ov;
    }
  }
}

// ---------------- host ----------------
extern "C" void kernel_launch(void* const* d_in, const int* in_sizes, int n_in,
                              void* d_out, int out_size, void* d_ws, size_t ws_size,
                              hipStream_t stream) {
  const float* hidden = (const float*)d_in[0];
  const float* cosb   = (const float*)d_in[1];
  const float* sinb   = (const float*)d_in[2];
  const float* Wq     = (const float*)d_in[3];
  const float* Wk     = (const float*)d_in[4];
  const float* Wv     = (const float*)d_in[5];
  const float* Wo     = (const float*)d_in[6];
  const float* qw     = (const float*)d_in[7];
  const float* kw     = (const float*)d_in[8];

  char* ws = (char*)d_ws;
  ushort* Xb    = (ushort*)ws; ws += (size_t)4096 * 2048 * 2;
  ushort* Wcomb = (ushort*)ws; ws += (size_t)4096 * 2048 * 2;
  ushort* Wob   = (ushort*)ws; ws += (size_t)2048 * 2048 * 2;
  ushort* QKVp  = (ushort*)ws; ws += (size_t)4096 * 4096 * 2;
  ushort* Qa    = (ushort*)ws; ws += (size_t)2 * 16 * 2048 * 128 * 2;
  ushort* Ka    = (ushort*)ws; ws += (size_t)2 * 8 * 2048 * 128 * 2;
  ushort* Vt    = (ushort*)ws; ws += (size_t)2 * 8 * 2048 * 128 * 2;
  ushort* Ctx   = (ushort*)ws; ws += (size_t)4096 * 2048 * 2;

  f2b8<<<4096, 256, 0, stream>>>(hidden, Xb, 8388608);
  wconv<<<6144, 256, 0, stream>>>(Wq, Wk, Wv, Wo, Wcomb, Wob);

  gemm256<0><<<dim3(16, 16), 512, 0, stream>>>(Xb, Wcomb, (void*)QKVp, 4096, 4096, 2048);

  qk_norm_rope<<<24576, 256, 0, stream>>>(QKVp, cosb, sinb, qw, kw, Qa, Ka);
  v_transpose<<<512, 256, 0, stream>>>(QKVp, Vt);

  attn_kernel<<<dim3(32, 16), 512, 0, stream>>>(Qa, Ka, Vt, Ctx);

  gemm128<<<dim3(32, 8), 512, 0, stream>>>(Ctx, Wob, (float*)d_out, 4096, 2048, 2048);
}

// Round 6
// 337.255 us; speedup vs baseline: 1.6351x; 1.0639x over previous
//
#include <hip/hip_runtime.h>

using short8 = __attribute__((ext_vector_type(8))) short;
using f32x4  = __attribute__((ext_vector_type(4))) float;
using f32x16 = __attribute__((ext_vector_type(16))) float;
using u32x2  = __attribute__((ext_vector_type(2))) unsigned int;
using u32x4  = __attribute__((ext_vector_type(4))) unsigned int;

#define MFMA16(a, b, c) __builtin_amdgcn_mfma_f32_16x16x32_bf16((a), (b), (c), 0, 0, 0)
#define MFMA32(a, b, c) __builtin_amdgcn_mfma_f32_32x32x16_bf16((a), (b), (c), 0, 0, 0)

__device__ inline float bf2f(ushort v) { return __uint_as_float(((unsigned int)v) << 16); }
__device__ inline unsigned int f2bfu(float f) {
  unsigned int u = __float_as_uint(f);
  return (u + 0x7fffu + ((u >> 16) & 1u)) >> 16;   // RNE
}
__device__ inline unsigned int pk2(float a, float b) { return f2bfu(a) | (f2bfu(b) << 16); }
__device__ inline unsigned int pk2hw(float lo, float hi) {
  unsigned int r;
  asm("v_cvt_pk_bf16_f32 %0, %1, %2" : "=v"(r) : "v"(lo), "v"(hi));
  return r;
}

__device__ inline void gl_lds16(const ushort* g, ushort* l) {
  __builtin_amdgcn_global_load_lds(
      (const __attribute__((address_space(1))) void*)g,
      (__attribute__((address_space(3))) void*)l, 16, 0, 0);
}

// ---------------- fp32 -> bf16 convert (hidden states) ----------------
__global__ __launch_bounds__(256) void f2b8(const float* __restrict__ src,
                                            ushort* __restrict__ dst, int n) {
  int i = (blockIdx.x * 256 + threadIdx.x) * 8;
  if (i >= n) return;
  f32x4 a = *(const f32x4*)(src + i);
  f32x4 b = *(const f32x4*)(src + i + 4);
  u32x4 o;
  o[0] = pk2(a[0], a[1]); o[1] = pk2(a[2], a[3]);
  o[2] = pk2(b[0], b[1]); o[3] = pk2(b[2], b[3]);
  *(u32x4*)(dst + i) = o;
}

// ---------------- merged weight converts ----------------
__global__ __launch_bounds__(256) void wconv(const float* __restrict__ Wq,
                                             const float* __restrict__ Wk,
                                             const float* __restrict__ Wv,
                                             const float* __restrict__ Wo,
                                             ushort* __restrict__ Wcomb,
                                             ushort* __restrict__ Wob) {
  int blk = blockIdx.x;
  const float* src; ushort* dst; int off;
  if (blk < 2048)      { src = Wq; dst = Wcomb;           off = blk * 2048; }
  else if (blk < 3072) { src = Wk; dst = Wcomb + 4194304; off = (blk - 2048) * 2048; }
  else if (blk < 4096) { src = Wv; dst = Wcomb + 6291456; off = (blk - 3072) * 2048; }
  else                 { src = Wo; dst = Wob;             off = (blk - 4096) * 2048; }
  int i = off + threadIdx.x * 8;
  f32x4 a = *(const f32x4*)(src + i);
  f32x4 b = *(const f32x4*)(src + i + 4);
  u32x4 o;
  o[0] = pk2(a[0], a[1]); o[1] = pk2(a[2], a[3]);
  o[2] = pk2(b[0], b[1]); o[3] = pk2(b[2], b[3]);
  *(u32x4*)(dst + i) = o;
}

// ---------------- 256x256 8-phase bf16 GEMM (QKV) ----------------
#define GPHASE(CB, P, STG, VMW)                                                     \
  {                                                                                 \
    if (P == 0) {                                                                   \
      _Pragma("unroll") for (int n = 0; n < 4; ++n) {                               \
        bf[n][0] = *(const short8*)&L[(CB)*32768 + bBase + n*1024 + rdoff];         \
        bf[n][1] = *(const short8*)&L[(CB)*32768 + bBase + n*1024 + (rdoff ^ 32)];  \
      }                                                                             \
    }                                                                               \
    short8 af[2][2];                                                                \
    _Pragma("unroll") for (int mi = 0; mi < 2; ++mi) {                              \
      af[mi][0] = *(const short8*)&L[(CB)*32768 + aBase + ((P)*2+mi)*1024 + rdoff];        \
      af[mi][1] = *(const short8*)&L[(CB)*32768 + aBase + ((P)*2+mi)*1024 + (rdoff ^ 32)]; \
    }                                                                               \
    STG;                                                                            \
    __builtin_amdgcn_s_barrier();                                                   \
    asm volatile("s_waitcnt lgkmcnt(0)" ::: "memory");                              \
    __builtin_amdgcn_s_setprio(1);                                                  \
    _Pragma("unroll") for (int mi = 0; mi < 2; ++mi)                                \
      _Pragma("unroll") for (int n = 0; n < 4; ++n) {                               \
        acc[(P)*2+mi][n] = MFMA16(af[mi][0], bf[n][0], acc[(P)*2+mi][n]);           \
        acc[(P)*2+mi][n] = MFMA16(af[mi][1], bf[n][1], acc[(P)*2+mi][n]);           \
      }                                                                             \
    __builtin_amdgcn_s_setprio(0);                                                  \
    VMW;                                                                            \
    __builtin_amdgcn_s_barrier();                                                   \
  }

#define VM4 asm volatile("s_waitcnt vmcnt(4)" ::: "memory")
#define NOPX (void)0

template <int OUTF32>
__global__ __launch_bounds__(512, 2) void gemm256(const ushort* __restrict__ A,
                                                  const ushort* __restrict__ B,
                                                  void* __restrict__ Cv,
                                                  int M, int N, int K) {
  __shared__ ushort L[65536];
  const int t = threadIdx.x;
  const int w = t >> 6, l = t & 63, lr = l & 15, lg = l >> 4;
  const int wr = w >> 2, wc = w & 3;
  const int m0 = blockIdx.x * 256, n0 = blockIdx.y * 256;
  const int NT = K >> 6, NI = NT >> 1;

  f32x4 acc[8][4] = {};

  const int rdoff = lr * 64 + ((lg ^ (lr & 7)) * 8);
  const int aBase = wr * 8192;
  const int bBase = 16384 + (wc >> 1) * 8192 + (wc & 1) * 4096;

  const int ch0 = w * 2, ch1 = w * 2 + 1;
  const int srow0 = ch0 * 8 + (l >> 3), srow1 = ch1 * 8 + (l >> 3);
  const int scol = ((l & 7) ^ (l >> 3)) * 8;

  auto stage_a = [&](int h, int kt, int cb) {
    int ktc = kt < NT ? kt : NT - 1;
    gl_lds16(A + (size_t)(m0 + h * 128 + srow0) * K + ktc * 64 + scol,
             (ushort*)&L[cb * 32768 + h * 8192 + ch0 * 512]);
    gl_lds16(A + (size_t)(m0 + h * 128 + srow1) * K + ktc * 64 + scol,
             (ushort*)&L[cb * 32768 + h * 8192 + ch1 * 512]);
  };
  auto stage_b = [&](int h, int kt, int cb) {
    int ktc = kt < NT ? kt : NT - 1;
    gl_lds16(B + (size_t)(n0 + h * 128 + srow0) * K + ktc * 64 + scol,
             (ushort*)&L[cb * 32768 + 16384 + h * 8192 + ch0 * 512]);
    gl_lds16(B + (size_t)(n0 + h * 128 + srow1) * K + ktc * 64 + scol,
             (ushort*)&L[cb * 32768 + 16384 + h * 8192 + ch1 * 512]);
  };

  stage_a(0, 0, 0); stage_a(1, 0, 0); stage_b(0, 0, 0); stage_b(1, 0, 0);
  stage_b(0, 1, 1); stage_b(1, 1, 1);
  VM4;
  __builtin_amdgcn_s_barrier();

  short8 bf[4][2];
  for (int I = 0; I < NI; ++I) {
    const int t1 = 2 * I + 1, t2 = 2 * I + 2, t3 = 2 * I + 3;
    GPHASE(0, 0, stage_a(0, t1, 1), NOPX)
    GPHASE(0, 1, stage_a(1, t1, 1), NOPX)
    GPHASE(0, 2, stage_b(0, t2, 0), NOPX)
    GPHASE(0, 3, stage_b(1, t2, 0), VM4)
    GPHASE(1, 0, stage_a(0, t2, 0), NOPX)
    GPHASE(1, 1, stage_a(1, t2, 0), NOPX)
    GPHASE(1, 2, stage_b(0, t3, 1), NOPX)
    GPHASE(1, 3, stage_b(1, t3, 1), VM4)
  }

  const int crow0 = m0 + wr * 128 + lg * 4;
  const int ccol = n0 + wc * 64 + lr;
  if (OUTF32) {
    float* C = (float*)Cv;
#pragma unroll
    for (int m = 0; m < 8; ++m)
#pragma unroll
      for (int n = 0; n < 4; ++n)
#pragma unroll
        for (int j = 0; j < 4; ++j)
          C[(size_t)(crow0 + m * 16 + j) * N + ccol + n * 16] = acc[m][n][j];
  } else {
    ushort* C = (ushort*)Cv;
#pragma unroll
    for (int m = 0; m < 8; ++m)
#pragma unroll
      for (int n = 0; n < 4; ++n)
#pragma unroll
        for (int j = 0; j < 4; ++j)
          C[(size_t)(crow0 + m * 16 + j) * N + ccol + n * 16] = (ushort)f2bfu(acc[m][n][j]);
  }
}

// ---------------- 128x256 8-phase bf16 GEMM, f32 out (Wo projection) ----------------
#define GP128(CB, P, STG, VMW)                                                      \
  {                                                                                 \
    if (P == 0) {                                                                   \
      _Pragma("unroll") for (int n = 0; n < 4; ++n) {                               \
        bf[n][0] = *(const short8*)&L[(CB)*24576 + bBase + n*1024 + rdoff];         \
        bf[n][1] = *(const short8*)&L[(CB)*24576 + bBase + n*1024 + (rdoff ^ 32)];  \
      }                                                                             \
    }                                                                               \
    short8 af0 = *(const short8*)&L[(CB)*24576 + aBase + (P)*1024 + rdoff];         \
    short8 af1 = *(const short8*)&L[(CB)*24576 + aBase + (P)*1024 + (rdoff ^ 32)];  \
    STG;                                                                            \
    __builtin_amdgcn_s_barrier();                                                   \
    asm volatile("s_waitcnt lgkmcnt(0)" ::: "memory");                              \
    __builtin_amdgcn_s_setprio(1);                                                  \
    _Pragma("unroll") for (int n = 0; n < 4; ++n) {                                 \
      acc[(P)][n] = MFMA16(af0, bf[n][0], acc[(P)][n]);                             \
      acc[(P)][n] = MFMA16(af1, bf[n][1], acc[(P)][n]);                             \
    }                                                                               \
    __builtin_amdgcn_s_setprio(0);                                                  \
    VMW;                                                                            \
    __builtin_amdgcn_s_barrier();                                                   \
  }

__global__ __launch_bounds__(512, 2) void gemm128(const ushort* __restrict__ A,
                                                  const ushort* __restrict__ B,
                                                  float* __restrict__ C,
                                                  int M, int N, int K) {
  __shared__ ushort L[49152];
  const int t = threadIdx.x;
  const int w = t >> 6, l = t & 63, lr = l & 15, lg = l >> 4;
  const int wr = w >> 2, wc = w & 3;
  const int m0 = blockIdx.x * 128, n0 = blockIdx.y * 256;
  const int NT = K >> 6, NI = NT >> 1;

  f32x4 acc[4][4] = {};

  const int rdoff = lr * 64 + ((lg ^ (lr & 7)) * 8);
  const int aBase = wr * 4096;
  const int bBase = 8192 + wc * 4096;
  const int scol = ((l & 7) ^ (l >> 3)) * 8;

  auto stage_a_h = [&](int h, int kt, int cb) {
    int ktc = kt < NT ? kt : NT - 1;
    int ch = h * 8 + w;
    gl_lds16(A + (size_t)(m0 + ch * 8 + (l >> 3)) * K + ktc * 64 + scol,
             (ushort*)&L[cb * 24576 + ch * 512]);
  };
  auto stage_b_h = [&](int h, int kt, int cb) {
    int ktc = kt < NT ? kt : NT - 1;
    int c0 = h * 16 + w * 2, c1 = c0 + 1;
    gl_lds16(B + (size_t)(n0 + c0 * 8 + (l >> 3)) * K + ktc * 64 + scol,
             (ushort*)&L[cb * 24576 + 8192 + c0 * 512]);
    gl_lds16(B + (size_t)(n0 + c1 * 8 + (l >> 3)) * K + ktc * 64 + scol,
             (ushort*)&L[cb * 24576 + 8192 + c1 * 512]);
  };

  stage_a_h(0, 0, 0); stage_a_h(1, 0, 0);
  stage_b_h(0, 0, 0); stage_b_h(1, 0, 0);
  stage_b_h(0, 1, 1); stage_b_h(1, 1, 1);
  VM4;
  __builtin_amdgcn_s_barrier();

  short8 bf[4][2];
  for (int I = 0; I < NI; ++I) {
    const int t1 = 2 * I + 1, t2 = 2 * I + 2, t3 = 2 * I + 3;
    GP128(0, 0, stage_a_h(0, t1, 1), NOPX)
    GP128(0, 1, stage_a_h(1, t1, 1), NOPX)
    GP128(0, 2, stage_b_h(0, t2, 0), NOPX)
    GP128(0, 3, stage_b_h(1, t2, 0), VM4)
    GP128(1, 0, stage_a_h(0, t2, 0), NOPX)
    GP128(1, 1, stage_a_h(1, t2, 0), NOPX)
    GP128(1, 2, stage_b_h(0, t3, 1), NOPX)
    GP128(1, 3, stage_b_h(1, t3, 1), VM4)
  }

  const int crow0 = m0 + wr * 64 + lg * 4;
  const int ccol = n0 + wc * 64 + lr;
#pragma unroll
  for (int m = 0; m < 4; ++m)
#pragma unroll
    for (int n = 0; n < 4; ++n)
#pragma unroll
      for (int j = 0; j < 4; ++j)
        C[(size_t)(crow0 + m * 16 + j) * N + ccol + n * 16] = acc[m][n][j];
}

// ---------------- RMSNorm + RoPE for Q and K ----------------
__global__ __launch_bounds__(256) void qk_norm_rope(
    const ushort* __restrict__ QKVp, const float* __restrict__ cosb,
    const float* __restrict__ sinb, const float* __restrict__ qw,
    const float* __restrict__ kw, ushort* __restrict__ Qa, ushort* __restrict__ Ka) {
  int r = blockIdx.x * 4 + (threadIdx.x >> 6);
  int i = threadIdx.x & 63;
  int b, s, srccol;
  ushort* dst;
  const float* w;
  float scale;
  if (r < 65536) {                       // Q rows
    b = r >> 15; int rem = r & 32767; s = rem >> 4; int h = rem & 15;
    srccol = h * 128;
    dst = Qa + ((size_t)((b * 16 + h) * 2048 + s)) * 128;
    w = qw;
    scale = 0.08838834764831845f * 1.4426950408889634f;  // HD^-0.5 * log2(e)
  } else {                               // K rows
    int rk = r - 65536;
    b = rk >> 14; int rem = rk & 16383; s = rem >> 3; int kvh = rem & 7;
    srccol = 2048 + kvh * 128;
    dst = Ka + ((size_t)((b * 8 + kvh) * 2048 + s)) * 128;
    w = kw;
    scale = 1.0f;
  }
  const ushort* src = QKVp + ((size_t)(b * 2048 + s)) * 4096 + srccol;
  float x0 = bf2f(src[i]), x1 = bf2f(src[i + 64]);
  float ss = x0 * x0 + x1 * x1;
#pragma unroll
  for (int m = 1; m < 64; m <<= 1) ss += __shfl_xor(ss, m);
  float inv = rsqrtf(ss * (1.0f / 128.0f) + 1e-6f);
  float xn0 = x0 * inv * w[i], xn1 = x1 * inv * w[i + 64];
  const float* cp = cosb + ((size_t)(b * 2048 + s)) * 128;
  const float* sp = sinb + ((size_t)(b * 2048 + s)) * 128;
  float o0 = (xn0 * cp[i] - xn1 * sp[i]) * scale;
  float o1 = (xn1 * cp[i + 64] + xn0 * sp[i + 64]) * scale;
  dst[i] = (ushort)f2bfu(o0);
  dst[i + 64] = (ushort)f2bfu(o1);
}

// ---------------- V transpose -> Vt[b][kvh][d][s] ----------------
__global__ __launch_bounds__(256) void v_transpose(const ushort* __restrict__ QKVp,
                                                   ushort* __restrict__ Vt) {
  __shared__ ushort tile[64][136];
  int blk = blockIdx.x;
  int st = blk & 31, kvh = (blk >> 5) & 7, b = blk >> 8;
  int t = threadIdx.x;
  int s0 = st * 64;
  {
    int r = t >> 2, cseg = (t & 3) * 32;
    const ushort* src = QKVp + ((size_t)(b * 2048 + s0 + r)) * 4096 + 3072 + kvh * 128 + cseg;
#pragma unroll
    for (int i = 0; i < 4; ++i)
      *(uint4*)&tile[r][cseg + i * 8] = *(const uint4*)(src + i * 8);
  }
  __syncthreads();
  {
    int d = t >> 1, sh = (t & 1) * 32;
    ushort* dst = Vt + ((size_t)((b * 8 + kvh) * 128 + d)) * 2048 + s0 + sh;
    ushort buf[32];
#pragma unroll
    for (int k = 0; k < 32; ++k) buf[k] = tile[sh + k][d];
#pragma unroll
    for (int i = 0; i < 4; ++i) *(uint4*)(dst + i * 8) = *(uint4*)&buf[i * 8];
  }
}

// ---------------- Flash attention v5: 32x32 swapped QK^T, in-register softmax ----------------
// 4 waves x 32 q-rows = 128 q/block, KVBLK=64, K/V dbuf + counted vmcnt(8).
// P stays in registers: cvt_pk_bf16 pairs + v_permlane32_swap build PV B-frags directly.
// C-layout (32x32): col=l&31, row=(reg&3)+8*(reg>>2)+4*(l>>5)  [m74/m101].
#define MKFRAG(S, B, OUT)                                               \
  {                                                                     \
    unsigned pw0 = pk2hw(S[B + 0], S[B + 1]);                           \
    unsigned pw1 = pk2hw(S[B + 2], S[B + 3]);                           \
    unsigned pw2 = pk2hw(S[B + 4], S[B + 5]);                           \
    unsigned pw3 = pk2hw(S[B + 6], S[B + 7]);                           \
    asm("v_permlane32_swap_b32 %0, %1" : "+v"(pw0), "+v"(pw2));         \
    asm("v_permlane32_swap_b32 %0, %1" : "+v"(pw1), "+v"(pw3));         \
    union { unsigned u[4]; short8 s; } _r;                              \
    _r.u[0] = pw0; _r.u[1] = pw1; _r.u[2] = pw2; _r.u[3] = pw3;         \
    OUT = _r.s;                                                         \
  }

__global__ __launch_bounds__(256, 2) void attn_kernel(const ushort* __restrict__ Qa,
                                                      const ushort* __restrict__ Ka,
                                                      const ushort* __restrict__ Vt,
                                                      ushort* __restrict__ Ctx) {
  __shared__ ushort Ks[2][64 * 128];   // [k][d], 16B slot ^= (k&15)
  __shared__ ushort Vs[2][128 * 64];   // [d][k], 16B slot ^= (d&7)
  __shared__ ushort Ot[4][32 * 40];    // per-wave O transpose scratch (40 = pad)
  const int bh = blockIdx.x, b = bh >> 4, h = bh & 15, kvh = h >> 1;
  const int t = threadIdx.x, w = t >> 6, l = t & 63;
  const int q = l & 31, hi = l >> 5;
  const int q0 = blockIdx.y * 128 + w * 32;
  const ushort* Qh = Qa + ((size_t)(b * 16 + h)) * 2048 * 128;
  const ushort* Kh = Ka + ((size_t)(b * 8 + kvh)) * 2048 * 128;
  const ushort* Vh = Vt + ((size_t)(b * 8 + kvh)) * 128 * 2048;

  // Q B-frags: col=q, d = dc*16 + hi*8 + 0..7
  short8 qf[8];
#pragma unroll
  for (int dc = 0; dc < 8; ++dc)
    qf[dc] = *(const short8*)&Qh[(size_t)(q0 + q) * 128 + dc * 16 + hi * 8];
  asm volatile("s_waitcnt vmcnt(0)" ::: "memory");   // exact vmcnt counting below

  f32x16 accO[4] = {};
  float mrun = -3.0e38f, lrun = 0.f;

  auto stage = [&](int kt0, ushort* KSB, ushort* VSB) {
#pragma unroll
    for (int i = 0; i < 4; ++i) {
      const int krow = w * 16 + i * 4 + (l >> 4);
      gl_lds16(Kh + (size_t)(kt0 + krow) * 128 + (((l & 15) ^ (krow & 15)) * 8),
               KSB + (w * 16 + i * 4) * 128);
      const int vrow = w * 32 + i * 8 + (l >> 3);
      gl_lds16(Vh + (size_t)vrow * 2048 + kt0 + (((l & 7) ^ (vrow & 7)) * 8),
               VSB + (w * 32 + i * 8) * 64);
    }
  };

  auto iter = [&](int kt, ushort* KSB, ushort* VSB) {
    // ---- QK^T: S^T[k][q], A=K rows k = kts*32+q', B=Q ----
    f32x16 s0 = {}, s1 = {};
    __builtin_amdgcn_s_setprio(1);
#pragma unroll
    for (int dc = 0; dc < 8; ++dc) {
      const int ksl = ((dc * 2 + hi) ^ (q & 15)) * 8;
      short8 ak0 = *(const short8*)&KSB[q * 128 + ksl];
      short8 ak1 = *(const short8*)&KSB[(32 + q) * 128 + ksl];
      s0 = MFMA32(ak0, qf[dc], s0);
      s1 = MFMA32(ak1, qf[dc], s1);
    }
    __builtin_amdgcn_s_setprio(0);

    // ---- in-register online softmax (lane owns 32 k for q; partner l^32 has other 32) ----
    float tm = -3.0e38f;
#pragma unroll
    for (int j = 0; j < 16; ++j) tm = fmaxf(tm, fmaxf(s0[j], s1[j]));
    tm = fmaxf(tm, __shfl_xor(tm, 32));
    if (!__all(tm <= mrun + 11.0f)) {              // T13 defer-rescale
      float nm = fmaxf(mrun, tm);
      float cf = __builtin_amdgcn_exp2f(mrun - nm);
#pragma unroll
      for (int d0 = 0; d0 < 4; ++d0)
#pragma unroll
        for (int j = 0; j < 16; ++j) accO[d0][j] *= cf;
      lrun *= cf;
      mrun = nm;
    }
    float ts = 0.f;
#pragma unroll
    for (int j = 0; j < 16; ++j) {
      float p0 = __builtin_amdgcn_exp2f(s0[j] - mrun);
      float p1 = __builtin_amdgcn_exp2f(s1[j] - mrun);
      s0[j] = p0; s1[j] = p1;
      ts += p0 + p1;
    }
    ts += __shfl_xor(ts, 32);
    lrun += ts;

    // ---- P -> PV B-frags in-register ----
    short8 pf0, pf1, pf2, pf3;
    MKFRAG(s0, 0, pf0) MKFRAG(s0, 8, pf1)
    MKFRAG(s1, 0, pf2) MKFRAG(s1, 8, pf3)

    // ---- PV: A=V rows d = d0*32+q', k-slots ks*2+hi ----
    __builtin_amdgcn_s_setprio(1);
#pragma unroll
    for (int d0 = 0; d0 < 4; ++d0) {
      const int vb = (d0 * 32 + q) * 64;
      const int vx = q & 7;
      short8 av0 = *(const short8*)&VSB[vb + ((0 + hi) ^ vx) * 8];
      short8 av1 = *(const short8*)&VSB[vb + ((2 + hi) ^ vx) * 8];
      short8 av2 = *(const short8*)&VSB[vb + ((4 + hi) ^ vx) * 8];
      short8 av3 = *(const short8*)&VSB[vb + ((6 + hi) ^ vx) * 8];
      accO[d0] = MFMA32(av0, pf0, accO[d0]);
      accO[d0] = MFMA32(av1, pf1, accO[d0]);
      accO[d0] = MFMA32(av2, pf2, accO[d0]);
      accO[d0] = MFMA32(av3, pf3, accO[d0]);
    }
    __builtin_amdgcn_s_setprio(0);

    // ---- pipeline: free buffer, refill with tile kt+128, wait tile kt+64 ----
    __builtin_amdgcn_s_barrier();
    if (kt + 128 < 2048) {
      stage(kt + 128, KSB, VSB);
      asm volatile("s_waitcnt vmcnt(8)" ::: "memory");
    } else {
      asm volatile("s_waitcnt vmcnt(0)" ::: "memory");
    }
    __builtin_amdgcn_s_barrier();
  };

  stage(0, Ks[0], Vs[0]);
  stage(64, Ks[1], Vs[1]);
  asm volatile("s_waitcnt vmcnt(8)" ::: "memory");
  __builtin_amdgcn_s_barrier();

  for (int t2 = 0; t2 < 2048; t2 += 128) {
    iter(t2,      Ks[0], Vs[0]);
    iter(t2 + 64, Ks[1], Vs[1]);
  }

  // ---- epilogue: normalize, transpose per d0-block via per-wave LDS, store 16B ----
  {
    float inv = 1.0f / lrun;
    ushort* ot = &Ot[w][0];
    const int q2 = l >> 1;
#pragma unroll
    for (int d0 = 0; d0 < 4; ++d0) {
#pragma unroll
      for (int p = 0; p < 8; ++p) {
        unsigned pw = pk2hw(accO[d0][2 * p] * inv, accO[d0][2 * p + 1] * inv);
        const int dw = (p & 1) + 4 * (p >> 1) + 2 * hi;   // dword index in 32-d row
        *(unsigned*)&ot[q * 40 + dw * 2] = pw;
      }
      // same-wave DS ops are in-order; reads below see the writes
#pragma unroll
      for (int r = 0; r < 2; ++r) {
        uint4 v = *(const uint4*)&ot[q2 * 40 + (l & 1) * 8 + r * 16];
        *(uint4*)&Ctx[(size_t)(b * 2048 + q0 + q2) * 2048 + h * 128 + d0 * 32 +
                      (l & 1) * 8 + r * 16] = v;
      }
    }
  }
}

// ---------------- host ----------------
extern "C" void kernel_launch(void* const* d_in, const int* in_sizes, int n_in,
                              void* d_out, int out_size, void* d_ws, size_t ws_size,
                              hipStream_t stream) {
  const float* hidden = (const float*)d_in[0];
  const float* cosb   = (const float*)d_in[1];
  const float* sinb   = (const float*)d_in[2];
  const float* Wq     = (const float*)d_in[3];
  const float* Wk     = (const float*)d_in[4];
  const float* Wv     = (const float*)d_in[5];
  const float* Wo     = (const float*)d_in[6];
  const float* qw     = (const float*)d_in[7];
  const float* kw     = (const float*)d_in[8];

  char* ws = (char*)d_ws;
  ushort* Xb    = (ushort*)ws; ws += (size_t)4096 * 2048 * 2;
  ushort* Wcomb = (ushort*)ws; ws += (size_t)4096 * 2048 * 2;
  ushort* Wob   = (ushort*)ws; ws += (size_t)2048 * 2048 * 2;
  ushort* QKVp  = (ushort*)ws; ws += (size_t)4096 * 4096 * 2;
  ushort* Qa    = (ushort*)ws; ws += (size_t)2 * 16 * 2048 * 128 * 2;
  ushort* Ka    = (ushort*)ws; ws += (size_t)2 * 8 * 2048 * 128 * 2;
  ushort* Vt    = (ushort*)ws; ws += (size_t)2 * 8 * 2048 * 128 * 2;
  ushort* Ctx   = (ushort*)ws; ws += (size_t)4096 * 2048 * 2;

  f2b8<<<4096, 256, 0, stream>>>(hidden, Xb, 8388608);
  wconv<<<6144, 256, 0, stream>>>(Wq, Wk, Wv, Wo, Wcomb, Wob);

  gemm256<0><<<dim3(16, 16), 512, 0, stream>>>(Xb, Wcomb, (void*)QKVp, 4096, 4096, 2048);

  qk_norm_rope<<<24576, 256, 0, stream>>>(QKVp, cosb, sinb, qw, kw, Qa, Ka);
  v_transpose<<<512, 256, 0, stream>>>(QKVp, Vt);

  attn_kernel<<<dim3(32, 16), 256, 0, stream>>>(Qa, Ka, Vt, Ctx);

  gemm128<<<dim3(32, 8), 512, 0, stream>>>(Ctx, Wob, (float*)d_out, 4096, 2048, 2048);
}